// Round 1
// baseline (195.011 us; speedup 1.0000x reference)
//
#include <hip/hip_runtime.h>
#include <cstddef>

#define NTOK 1024
#define DMODEL 512
#define NHEAD 8
#define DKH 64

__device__ __forceinline__ float wave_max_f(float v){
  #pragma unroll
  for (int m=1; m<64; m<<=1) v = fmaxf(v, __shfl_xor(v, m, 64));
  return v;
}
__device__ __forceinline__ float wave_sum_f(float v){
  #pragma unroll
  for (int m=1; m<64; m<<=1) v += __shfl_xor(v, m, 64);
  return v;
}

// ---------------- box prep: cx, cy, w, h, log w, log h ----------------
__global__ void k_box(const float* __restrict__ box, float* __restrict__ bx){
  int i = blockIdx.x*blockDim.x + threadIdx.x;
  if (i >= NTOK) return;
  float xmin = box[i*4+0], ymin = box[i*4+1], xmax = box[i*4+2], ymax = box[i*4+3];
  float cx = (xmin+xmax)*0.5f, cy = (ymin+ymax)*0.5f;
  float w = xmax-xmin+1.0f, h = ymax-ymin+1.0f;
  bx[i] = cx; bx[NTOK+i] = cy; bx[2*NTOK+i] = w; bx[3*NTOK+i] = h;
  bx[4*NTOK+i] = __logf(w); bx[5*NTOK+i] = __logf(h);
}

// ---------------- gating: glog[h][i][j] = log(clip(relu(emb . WGw + WGb), 1e-6)) ----------------
// block 256 = 64 j x 4 i; trig computed once per (i,j) pair in registers.
__global__ __launch_bounds__(256) void k_gate(const float* __restrict__ bx,
        const float* __restrict__ WGw, const float* __restrict__ WGb,
        float* __restrict__ glog){
  const int t = threadIdx.x;
  const int j = (blockIdx.x & 15)*64 + (t & 63);
  const int i = (blockIdx.x >> 4)*4 + (t >> 6);
  const float* cx = bx;
  const float* cy = bx + NTOK;
  const float* ww = bx + 2*NTOK;
  const float* hh = bx + 3*NTOK;
  const float* lw = bx + 4*NTOK;
  const float* lh = bx + 5*NTOK;
  float cxi = cx[i], cyi = cy[i];
  float rwi = 1.0f/ww[i], rhi = 1.0f/hh[i];
  float dx = __logf(fmaxf(fabsf((cxi - cx[j])*rwi), 1e-3f));
  float dy = __logf(fmaxf(fabsf((cyi - cy[j])*rhi), 1e-3f));
  float dw = lw[i] - lw[j];
  float dh = lh[i] - lh[j];
  // 100 * 1000^(-d/8), d = 0..7
  const float DM[8] = {100.0f, 42.16965f, 17.782794f, 7.4989421f,
                       3.1622777f, 1.3335214f, 0.56234133f, 0.23713737f};
  float pos[4] = {dx, dy, dw, dh};
  float sv[32], cv[32];
  #pragma unroll
  for (int p=0; p<4; p++){
    #pragma unroll
    for (int d=0; d<8; d++){
      float ang = pos[p]*DM[d];
      __sincosf(ang, &sv[p*8+d], &cv[p*8+d]);
    }
  }
  #pragma unroll
  for (int h=0; h<8; h++){
    float gd = WGb[h];
    #pragma unroll
    for (int a=0; a<32; a++)
      gd = fmaf(sv[a], WGw[h*64+a], fmaf(cv[a], WGw[h*64+32+a], gd));
    glog[((size_t)h<<20) + ((size_t)i<<10) + j] = __logf(fmaxf(gd, 1e-6f));
  }
}

// ---------------- fp32 GEMM: C[m][n] = sum_k A[m][k]*W[n][k] + bias[n] (+ add[m][n]) ----------------
// 64x64 tile, K-transposed XOR-swizzled LDS (conflict-free b128 reads), 4x4 per thread.
__device__ __forceinline__ void gemm_body(const float* __restrict__ A, const float* __restrict__ W,
       const float* __restrict__ bias, const float* __restrict__ add, float* __restrict__ C){
  constexpr int K = DMODEL, Nc = DMODEL;
  __shared__ float As[64*64];
  __shared__ float Ws[64*64];
  const int t = threadIdx.x;
  const int tx = t & 15, ty = t >> 4;
  const int n0 = blockIdx.x*64, m0 = blockIdx.y*64;
  float acc[4][4] = {};
  for (int k0 = 0; k0 < K; k0 += 64){
    __syncthreads();
    #pragma unroll
    for (int it = 0; it < 4; ++it){
      int idx = t + it*256;
      int row = idx >> 4, kq = idx & 15;
      float4 a  = *(const float4*)(A + (size_t)(m0+row)*K + k0 + kq*4);
      float4 wv = *(const float4*)(W + (size_t)(n0+row)*K + k0 + kq*4);
      const float* af = (const float*)&a; const float* wf = (const float*)&wv;
      #pragma unroll
      for (int q=0; q<4; q++){
        int k = kq*4+q;
        int sw = ((k>>2)&7)<<2;                 // XOR-swizzle keeps b128 reads conflict-free
        As[k*64 + (row ^ sw)] = af[q];
        Ws[k*64 + (row ^ sw)] = wf[q];
      }
    }
    __syncthreads();
    #pragma unroll 8
    for (int kk=0; kk<64; ++kk){
      int sw = ((kk>>2)&7)<<2;
      float4 av = *(const float4*)&As[kk*64 + ((ty*4)^sw)];
      float4 wv = *(const float4*)&Ws[kk*64 + ((tx*4)^sw)];
      const float* af=(const float*)&av; const float* wf=(const float*)&wv;
      #pragma unroll
      for (int r=0; r<4; r++)
        #pragma unroll
        for (int c=0; c<4; c++)
          acc[r][c] = fmaf(af[r], wf[c], acc[r][c]);
    }
  }
  #pragma unroll
  for (int r=0; r<4; r++){
    int mrow = m0 + ty*4 + r;
    int nc0 = n0 + tx*4;
    float4 bv = *(const float4*)(bias + nc0);
    float4 o;
    o.x = acc[r][0]+bv.x; o.y = acc[r][1]+bv.y;
    o.z = acc[r][2]+bv.z; o.w = acc[r][3]+bv.w;
    if (add){
      float4 ad = *(const float4*)(add + (size_t)mrow*Nc + nc0);
      o.x += ad.x; o.y += ad.y; o.z += ad.z; o.w += ad.w;
    }
    *(float4*)(C + (size_t)mrow*Nc + nc0) = o;
  }
}

__global__ __launch_bounds__(256) void k_gemm_qkv(
    const float* __restrict__ Aq, const float* __restrict__ Ak, const float* __restrict__ Av,
    const float* __restrict__ Wq, const float* __restrict__ Wk, const float* __restrict__ Wv,
    const float* __restrict__ bq, const float* __restrict__ bk, const float* __restrict__ bv,
    float* __restrict__ Cq, float* __restrict__ Ck, float* __restrict__ Cv){
  const float* A; const float* W; const float* bias; float* C;
  switch (blockIdx.z){
    case 0:  A=Aq; W=Wq; bias=bq; C=Cq; break;
    case 1:  A=Ak; W=Wk; bias=bk; C=Ck; break;
    default: A=Av; W=Wv; bias=bv; C=Cv; break;
  }
  gemm_body(A, W, bias, nullptr, C);
}

__global__ __launch_bounds__(256) void k_gemm_o(const float* __restrict__ A, const float* __restrict__ W,
    const float* __restrict__ bias, const float* __restrict__ add, float* __restrict__ C){
  gemm_body(A, W, bias, add, C);
}

// ---------------- flash attention per (head, 16-row tile) ----------------
// logits = glog[h][i][j] + (q.k)/8, online softmax over j, PV accumulate.
__global__ __launch_bounds__(256) void k_attn(const float* __restrict__ Qp, const float* __restrict__ Kp,
       const float* __restrict__ Vp, const float* __restrict__ glog, float* __restrict__ Xh){
  const int h = blockIdx.y;
  const int i0 = blockIdx.x*16;
  const int t = threadIdx.x, lane = t & 63;
  const int w = __builtin_amdgcn_readfirstlane(t >> 6);   // wave id (uniform -> enables s_load of Q)
  __shared__ float kt[64*68];
  __shared__ float vt[64*68];
  __shared__ float ps[64*20];
  const float* qb = Qp + (size_t)(i0 + w*4)*DMODEL + h*DKH;
  const float* gb = glog + ((size_t)h<<20) + ((size_t)(i0 + w*4)<<10);
  float m[4] = {-1e30f,-1e30f,-1e30f,-1e30f};
  float l[4] = {0.f,0.f,0.f,0.f};
  float acc[4] = {0.f,0.f,0.f,0.f};        // lane plays role dk=lane here
  for (int j0=0; j0<NTOK; j0+=64){
    __syncthreads();
    #pragma unroll
    for (int it=0; it<4; ++it){
      int idx = t + it*256;
      int j = idx >> 4, dq = idx & 15;
      *(float4*)&kt[j*68 + dq*4] = *(const float4*)(Kp + (size_t)(j0+j)*DMODEL + h*DKH + dq*4);
      *(float4*)&vt[j*68 + dq*4] = *(const float4*)(Vp + (size_t)(j0+j)*DMODEL + h*DKH + dq*4);
    }
    __syncthreads();
    // scores: lane = j within tile
    float s0=0.f, s1=0.f, s2=0.f, s3=0.f;
    #pragma unroll
    for (int dk4=0; dk4<16; ++dk4){
      float4 kv = *(const float4*)&kt[lane*68 + dk4*4];
      const float* kf = (const float*)&kv;
      #pragma unroll
      for (int q=0; q<4; q++){
        float kq = kf[q];
        s0 = fmaf(kq, qb[0*DMODEL + dk4*4+q], s0);
        s1 = fmaf(kq, qb[1*DMODEL + dk4*4+q], s1);
        s2 = fmaf(kq, qb[2*DMODEL + dk4*4+q], s2);
        s3 = fmaf(kq, qb[3*DMODEL + dk4*4+q], s3);
      }
    }
    float sc4[4] = {s0,s1,s2,s3};
    #pragma unroll
    for (int r=0; r<4; r++){
      float e = gb[(size_t)r*NTOK + j0 + lane] + sc4[r]*0.125f;
      float tm = wave_max_f(e);
      float nm = fmaxf(m[r], tm);
      float scl = __expf(m[r]-nm);
      float p = __expf(e-nm);
      float tsum = wave_sum_f(p);
      l[r] = l[r]*scl + tsum;
      m[r] = nm;
      acc[r] *= scl;
      ps[lane*20 + w*4 + r] = p;
    }
    __syncthreads();
    // PV: lane = dk
    #pragma unroll 8
    for (int j=0; j<64; j++){
      float v = vt[j*68 + lane];
      float4 p4 = *(const float4*)&ps[j*20 + w*4];
      acc[0] = fmaf(p4.x, v, acc[0]);
      acc[1] = fmaf(p4.y, v, acc[1]);
      acc[2] = fmaf(p4.z, v, acc[2]);
      acc[3] = fmaf(p4.w, v, acc[3]);
    }
  }
  #pragma unroll
  for (int r=0; r<4; r++){
    Xh[((size_t)h*NTOK + i0 + w*4 + r)*DKH + lane] = acc[r]/l[r];
  }
}

// ---------------- LN with the faithful scrambled reshape + residual ----------------
// attn[n][d] = x[h = n>>7][m = (n&1)*512 + d][dk = (n>>1)&63]
__global__ __launch_bounds__(256) void k_ln0(const float* __restrict__ Xh, const float* __restrict__ resid,
        const float* __restrict__ g, const float* __restrict__ b, float* __restrict__ out0){
  const int n = blockIdx.x, t = threadIdx.x;
  const int h = n >> 7, dk = (n >> 1) & 63, mo = (n & 1)*512;
  float x0 = Xh[((size_t)h*NTOK + mo + t)*DKH + dk]       + resid[(size_t)n*DMODEL + t];
  float x1 = Xh[((size_t)h*NTOK + mo + t + 256)*DKH + dk] + resid[(size_t)n*DMODEL + t + 256];
  __shared__ float red[8];
  float s = wave_sum_f(x0 + x1);
  float q = wave_sum_f(x0*x0 + x1*x1);
  int wid = t >> 6, lane = t & 63;
  if (lane == 0){ red[wid] = s; red[4+wid] = q; }
  __syncthreads();
  float S = red[0]+red[1]+red[2]+red[3];
  float Q = red[4]+red[5]+red[6]+red[7];
  float mean = S * (1.0f/512.0f);
  float var = Q * (1.0f/512.0f) - mean*mean;
  float rs = rsqrtf(var + 1e-5f);
  out0[(size_t)n*DMODEL + t]       = (x0-mean)*rs*g[t] + b[t];
  out0[(size_t)n*DMODEL + t + 256] = (x1-mean)*rs*g[t+256] + b[t+256];
}

__global__ __launch_bounds__(256) void k_lnf(const float* __restrict__ x, const float* __restrict__ g,
        const float* __restrict__ b, float* __restrict__ out){
  const int n = blockIdx.x, t = threadIdx.x;
  float x0 = x[(size_t)n*DMODEL + t];
  float x1 = x[(size_t)n*DMODEL + t + 256];
  __shared__ float red[8];
  float s = wave_sum_f(x0 + x1);
  float q = wave_sum_f(x0*x0 + x1*x1);
  int wid = t >> 6, lane = t & 63;
  if (lane == 0){ red[wid] = s; red[4+wid] = q; }
  __syncthreads();
  float S = red[0]+red[1]+red[2]+red[3];
  float Q = red[4]+red[5]+red[6]+red[7];
  float mean = S * (1.0f/512.0f);
  float var = Q * (1.0f/512.0f) - mean*mean;
  float rs = rsqrtf(var + 1e-5f);
  out[(size_t)n*DMODEL + t]       = (x0-mean)*rs*g[t] + b[t];
  out[(size_t)n*DMODEL + t + 256] = (x1-mean)*rs*g[t+256] + b[t+256];
}

extern "C" void kernel_launch(void* const* d_in, const int* in_sizes, int n_in,
                              void* d_out, int out_size, void* d_ws, size_t ws_size,
                              hipStream_t stream){
  (void)in_sizes; (void)n_in; (void)out_size; (void)ws_size;
  const float* in_q = (const float*)d_in[0];
  const float* in_k = (const float*)d_in[1];
  const float* in_v = (const float*)d_in[2];
  const float* box  = (const float*)d_in[3];
  const float* Wq   = (const float*)d_in[4];
  const float* bq   = (const float*)d_in[5];
  const float* Wk   = (const float*)d_in[6];
  const float* bk   = (const float*)d_in[7];
  const float* Wv   = (const float*)d_in[8];
  const float* bv   = (const float*)d_in[9];
  const float* Wo   = (const float*)d_in[10];
  const float* bo   = (const float*)d_in[11];
  const float* WGw  = (const float*)d_in[12];
  const float* WGb  = (const float*)d_in[13];
  const float* ln0g = (const float*)d_in[14];
  const float* ln0b = (const float*)d_in[15];
  const float* lng  = (const float*)d_in[16];
  const float* lnb  = (const float*)d_in[17];

  float* ws  = (float*)d_ws;
  float* bx   = ws;                  // 6144 floats
  float* Qp   = ws + 8192;           // [1024][512]
  float* Kp   = Qp + 524288;
  float* Vp   = Kp + 524288;
  float* Xh   = Vp + 524288;         // [8][1024][64]
  float* glog = Xh + 524288;         // [8][1024][1024]  (32 MB)
  float* out0 = Qp;                  // reuse: Qp dead after k_attn
  float* tmp  = Kp;                  // reuse: Kp dead after k_attn
  float* out  = (float*)d_out;

  k_box<<<dim3(4), dim3(256), 0, stream>>>(box, bx);
  k_gate<<<dim3(4096), dim3(256), 0, stream>>>(bx, WGw, WGb, glog);
  k_gemm_qkv<<<dim3(8,16,3), dim3(256), 0, stream>>>(in_q, in_k, in_v,
            Wq, Wk, Wv, bq, bk, bv, Qp, Kp, Vp);
  k_attn<<<dim3(64,8), dim3(256), 0, stream>>>(Qp, Kp, Vp, glog, Xh);
  k_ln0<<<dim3(1024), dim3(256), 0, stream>>>(Xh, in_q, ln0g, ln0b, out0);
  k_gemm_o<<<dim3(8,16), dim3(256), 0, stream>>>(out0, Wo, bo, out0, tmp);
  k_lnf<<<dim3(1024), dim3(256), 0, stream>>>(tmp, lng, lnb, out);
}

// Round 2
// 148.862 us; speedup vs baseline: 1.3100x; 1.3100x over previous
//
#include <hip/hip_runtime.h>
#include <cstddef>

#define NTOK 1024
#define DMODEL 512
#define NHEAD 8
#define DKH 64
#define NSPLIT 4

typedef __attribute__((ext_vector_type(4))) float f32x4;
typedef __attribute__((ext_vector_type(8))) __bf16 bf16x8;
typedef __attribute__((ext_vector_type(4))) __bf16 bf16x4;
typedef __attribute__((ext_vector_type(4))) unsigned short u16x4;
typedef unsigned short ushort_t;

__device__ __forceinline__ float wave_sum_f(float v){
  #pragma unroll
  for (int m=1; m<64; m<<=1) v += __shfl_xor(v, m, 64);
  return v;
}

__device__ __forceinline__ unsigned short f2bf(float f){
  __bf16 b = (__bf16)f;
  return __builtin_bit_cast(unsigned short, b);
}

// ---------------- box prep: cx, cy, w, h, log w, log h ----------------
__global__ void k_box(const float* __restrict__ box, float* __restrict__ bx){
  int i = blockIdx.x*blockDim.x + threadIdx.x;
  if (i >= NTOK) return;
  float xmin = box[i*4+0], ymin = box[i*4+1], xmax = box[i*4+2], ymax = box[i*4+3];
  float cx = (xmin+xmax)*0.5f, cy = (ymin+ymax)*0.5f;
  float w = xmax-xmin+1.0f, h = ymax-ymin+1.0f;
  bx[i] = cx; bx[NTOK+i] = cy; bx[2*NTOK+i] = w; bx[3*NTOK+i] = h;
  bx[4*NTOK+i] = __logf(w); bx[5*NTOK+i] = __logf(h);
}

// ---------------- gating: glog[h][i][j] = log(clip(relu(emb . WGw + WGb), 1e-6)) ----------------
__global__ __launch_bounds__(256) void k_gate(const float* __restrict__ bx,
        const float* __restrict__ WGw, const float* __restrict__ WGb,
        float* __restrict__ glog){
  const int t = threadIdx.x;
  const int j = (blockIdx.x & 15)*64 + (t & 63);
  const int i = (blockIdx.x >> 4)*4 + (t >> 6);
  const float* cx = bx;
  const float* cy = bx + NTOK;
  const float* ww = bx + 2*NTOK;
  const float* hh = bx + 3*NTOK;
  const float* lw = bx + 4*NTOK;
  const float* lh = bx + 5*NTOK;
  float cxi = cx[i], cyi = cy[i];
  float rwi = 1.0f/ww[i], rhi = 1.0f/hh[i];
  float dx = __logf(fmaxf(fabsf((cxi - cx[j])*rwi), 1e-3f));
  float dy = __logf(fmaxf(fabsf((cyi - cy[j])*rhi), 1e-3f));
  float dw = lw[i] - lw[j];
  float dh = lh[i] - lh[j];
  const float DM[8] = {100.0f, 42.16965f, 17.782794f, 7.4989421f,
                       3.1622777f, 1.3335214f, 0.56234133f, 0.23713737f};
  float pos[4] = {dx, dy, dw, dh};
  float sv[32], cv[32];
  #pragma unroll
  for (int p=0; p<4; p++){
    #pragma unroll
    for (int d=0; d<8; d++){
      float ang = pos[p]*DM[d];
      __sincosf(ang, &sv[p*8+d], &cv[p*8+d]);
    }
  }
  #pragma unroll
  for (int h=0; h<8; h++){
    float gd = WGb[h];
    #pragma unroll
    for (int a=0; a<32; a++)
      gd = fmaf(sv[a], WGw[h*64+a], fmaf(cv[a], WGw[h*64+32+a], gd));
    glog[((size_t)h<<20) + ((size_t)i<<10) + j] = __logf(fmaxf(gd, 1e-6f));
  }
}

// ---------------- fp32 GEMM core (64x64 tile, XOR-swizzled LDS, 4x4/thread) ----------------
__device__ __forceinline__ void gemm_core(const float* __restrict__ A, const float* __restrict__ W,
       float acc[4][4]){
  constexpr int K = DMODEL;
  __shared__ float As[64*64];
  __shared__ float Ws[64*64];
  const int t = threadIdx.x;
  const int tx = t & 15, ty = t >> 4;
  const int n0 = blockIdx.x*64, m0 = blockIdx.y*64;
  for (int k0 = 0; k0 < K; k0 += 64){
    __syncthreads();
    #pragma unroll
    for (int it = 0; it < 4; ++it){
      int idx = t + it*256;
      int row = idx >> 4, kq = idx & 15;
      float4 a  = *(const float4*)(A + (size_t)(m0+row)*K + k0 + kq*4);
      float4 wv = *(const float4*)(W + (size_t)(n0+row)*K + k0 + kq*4);
      const float* af = (const float*)&a; const float* wf = (const float*)&wv;
      #pragma unroll
      for (int q=0; q<4; q++){
        int k = kq*4+q;
        int sw = ((k>>2)&7)<<2;
        As[k*64 + (row ^ sw)] = af[q];
        Ws[k*64 + (row ^ sw)] = wf[q];
      }
    }
    __syncthreads();
    #pragma unroll 8
    for (int kk=0; kk<64; ++kk){
      int sw = ((kk>>2)&7)<<2;
      float4 av = *(const float4*)&As[kk*64 + ((ty*4)^sw)];
      float4 wv = *(const float4*)&Ws[kk*64 + ((tx*4)^sw)];
      const float* af=(const float*)&av; const float* wf=(const float*)&wv;
      #pragma unroll
      for (int r=0; r<4; r++)
        #pragma unroll
        for (int c=0; c<4; c++)
          acc[r][c] = fmaf(af[r], wf[c], acc[r][c]);
    }
  }
}

// QKV projection -> bf16 outputs: Qb/Kb row-major [1024][512], Vt per-head transposed [8][64][1024]
__global__ __launch_bounds__(256) void k_gemm_qkv_b(
    const float* __restrict__ Aq, const float* __restrict__ Ak, const float* __restrict__ Av,
    const float* __restrict__ Wq, const float* __restrict__ Wk, const float* __restrict__ Wv,
    const float* __restrict__ bq, const float* __restrict__ bk, const float* __restrict__ bv,
    ushort_t* __restrict__ Cq, ushort_t* __restrict__ Ck, ushort_t* __restrict__ Vt){
  const float* A; const float* W; const float* bias;
  switch (blockIdx.z){
    case 0:  A=Aq; W=Wq; bias=bq; break;
    case 1:  A=Ak; W=Wk; bias=bk; break;
    default: A=Av; W=Wv; bias=bv; break;
  }
  float acc[4][4] = {};
  gemm_core(A, W, acc);
  const int t = threadIdx.x;
  const int tx = t & 15, ty = t >> 4;
  const int n0 = blockIdx.x*64, m0 = blockIdx.y*64;
  const int nc0 = n0 + tx*4;
  float4 bv4 = *(const float4*)(bias + nc0);
  const float* bf_ = (const float*)&bv4;
  if (blockIdx.z < 2){
    ushort_t* C = blockIdx.z ? Ck : Cq;
    #pragma unroll
    for (int r=0; r<4; r++){
      int mrow = m0 + ty*4 + r;
      u16x4 o;
      #pragma unroll
      for (int c=0; c<4; c++) o[c] = f2bf(acc[r][c] + bf_[c]);
      *(u16x4*)(C + (size_t)mrow*DMODEL + nc0) = o;
    }
  } else {
    #pragma unroll
    for (int r=0; r<4; r++){
      int j = m0 + ty*4 + r;
      #pragma unroll
      for (int c=0; c<4; c++){
        int n = nc0 + c;
        Vt[(((size_t)(n>>6))<<16) + ((size_t)(n&63)<<10) + j] = f2bf(acc[r][c] + bf_[c]);
      }
    }
  }
}

// O-projection (fp32 out, fused +add)
__global__ __launch_bounds__(256) void k_gemm_o(const float* __restrict__ A, const float* __restrict__ W,
    const float* __restrict__ bias, const float* __restrict__ add, float* __restrict__ C){
  float acc[4][4] = {};
  gemm_core(A, W, acc);
  const int t = threadIdx.x;
  const int tx = t & 15, ty = t >> 4;
  const int n0 = blockIdx.x*64, m0 = blockIdx.y*64;
  #pragma unroll
  for (int r=0; r<4; r++){
    int mrow = m0 + ty*4 + r;
    int nc0 = n0 + tx*4;
    float4 bv = *(const float4*)(bias + nc0);
    float4 ad = *(const float4*)(add + (size_t)mrow*DMODEL + nc0);
    float4 o;
    o.x = acc[r][0]+bv.x+ad.x; o.y = acc[r][1]+bv.y+ad.y;
    o.z = acc[r][2]+bv.z+ad.z; o.w = acc[r][3]+bv.w+ad.w;
    *(float4*)(C + (size_t)mrow*DMODEL + nc0) = o;
  }
}

// ---------------- MFMA attention: S^T = mfma(K,Q); p=exp(glog+s/8); X^T += mfma(Vt,P^T) ----------------
// Per wave: one (16-row i-tile, head, j-split). No LDS, no syncthreads, no max pass
// (logits bounded: glog<=~2, |s|<=~2, exp safe in fp32). Partials combine by addition.
__global__ __launch_bounds__(256) void k_attn2(const ushort_t* __restrict__ Qb,
     const ushort_t* __restrict__ Kb, const ushort_t* __restrict__ Vt,
     const float* __restrict__ glog, ushort_t* __restrict__ Xpb, float* __restrict__ rsp){
  const int t = threadIdx.x;
  const int lane = t & 63;
  const int w = t >> 6;
  const int id = blockIdx.x*4 + w;
  const int it = id & 63;
  const int h  = (id >> 6) & 7;
  const int sp = id >> 9;
  const int i0 = it*16;
  const int li = lane & 15, g = lane >> 4;

  // Q B-frags (col index = i), k-chunks 0-31 / 32-63
  const ushort_t* qp = Qb + (size_t)(i0+li)*DMODEL + h*DKH + g*8;
  bf16x8 qf0 = *(const bf16x8*)(qp);
  bf16x8 qf1 = *(const bf16x8*)(qp + 32);

  f32x4 xacc[4];
  #pragma unroll
  for (int mf=0; mf<4; mf++) xacc[mf] = (f32x4){0.f,0.f,0.f,0.f};
  float rsum = 0.f;

  const ushort_t* kbase = Kb + (size_t)li*DMODEL + h*DKH + g*8;
  const float*    gbase = glog + ((size_t)h<<20) + ((size_t)(i0+li)<<10) + g*4;
  const ushort_t* vbase = Vt + ((size_t)h<<16) + (size_t)li*NTOK + g*4;

  const int jbeg = sp*(NTOK/NSPLIT), jend = jbeg + NTOK/NSPLIT;
  for (int j0 = jbeg; j0 < jend; j0 += 32){
    // QK^T (swapped): rows = j, cols = i
    const ushort_t* kp = kbase + (size_t)j0*DMODEL;
    bf16x8 a00 = *(const bf16x8*)(kp);
    bf16x8 a01 = *(const bf16x8*)(kp + 32);
    bf16x8 a10 = *(const bf16x8*)(kp + 16*DMODEL);
    bf16x8 a11 = *(const bf16x8*)(kp + 16*DMODEL + 32);
    f32x4 s0 = (f32x4){0.f,0.f,0.f,0.f};
    f32x4 s1 = (f32x4){0.f,0.f,0.f,0.f};
    s0 = __builtin_amdgcn_mfma_f32_16x16x32_bf16(a00, qf0, s0, 0,0,0);
    s0 = __builtin_amdgcn_mfma_f32_16x16x32_bf16(a01, qf1, s0, 0,0,0);
    s1 = __builtin_amdgcn_mfma_f32_16x16x32_bf16(a10, qf0, s1, 0,0,0);
    s1 = __builtin_amdgcn_mfma_f32_16x16x32_bf16(a11, qf1, s1, 0,0,0);
    // logits + exp.  Lane holds (i = li, j = j0 + 16*nt + 4*g + reg)
    f32x4 g0 = *(const f32x4*)(gbase + j0);
    f32x4 g1 = *(const f32x4*)(gbase + j0 + 16);
    float p[8];
    #pragma unroll
    for (int r=0; r<4; r++){ p[r]   = __expf(g0[r] + s0[r]*0.125f); rsum += p[r]; }
    #pragma unroll
    for (int r=0; r<4; r++){ p[4+r] = __expf(g1[r] + s1[r]*0.125f); rsum += p[4+r]; }
    // pack P^T B-frag: slot (g, e) holds j = j0 + 16*(e>>2) + 4*g + (e&3)
    bf16x8 pb;
    pb[0]=(__bf16)p[0]; pb[1]=(__bf16)p[1]; pb[2]=(__bf16)p[2]; pb[3]=(__bf16)p[3];
    pb[4]=(__bf16)p[4]; pb[5]=(__bf16)p[5]; pb[6]=(__bf16)p[6]; pb[7]=(__bf16)p[7];
    // PV: A-frags from Vt with the SAME slot->j permutation -> two 8B loads each
    #pragma unroll
    for (int mf=0; mf<4; mf++){
      const ushort_t* vp = vbase + (size_t)mf*16*NTOK + j0;
      bf16x4 lo = *(const bf16x4*)(vp);
      bf16x4 hi = *(const bf16x4*)(vp + 16);
      bf16x8 vf = __builtin_shufflevector(lo, hi, 0,1,2,3,4,5,6,7);
      xacc[mf] = __builtin_amdgcn_mfma_f32_16x16x32_bf16(vf, pb, xacc[mf], 0,0,0);
    }
  }
  // row-sum: reduce over the 4 lane-groups holding the same i
  rsum += __shfl_xor(rsum, 16, 64);
  rsum += __shfl_xor(rsum, 32, 64);
  if (lane < 16) rsp[((size_t)sp*NHEAD + h)*NTOK + i0 + li] = rsum;
  // store partial X (bf16): lane holds (i = li, d = mf*16 + 4*g + reg)
  ushort_t* xp = Xpb + ((((size_t)sp*NHEAD + h)*NTOK) + i0 + li)*DKH + g*4;
  #pragma unroll
  for (int mf=0; mf<4; mf++){
    u16x4 o;
    #pragma unroll
    for (int r=0; r<4; r++) o[r] = f2bf(xacc[mf][r]);
    *(u16x4*)(xp + mf*16) = o;
  }
}

// combine j-split partials: Xh[h][i][d] = sum_sp Xp / sum_sp rs
__global__ __launch_bounds__(256) void k_combine(const ushort_t* __restrict__ Xpb,
        const float* __restrict__ rsp, float* __restrict__ Xh){
  int gid = blockIdx.x*256 + threadIdx.x;   // 131072 threads: (h, i, d4)
  int d4 = gid & 15;
  int i  = (gid >> 4) & 1023;
  int h  = gid >> 14;
  float a0=0.f, a1=0.f, a2=0.f, a3=0.f, rs=0.f;
  #pragma unroll
  for (int sp=0; sp<NSPLIT; sp++){
    const ushort_t* p = Xpb + ((((size_t)sp*NHEAD + h)*NTOK) + i)*DKH + d4*4;
    bf16x4 v = *(const bf16x4*)p;
    a0 += (float)v[0]; a1 += (float)v[1]; a2 += (float)v[2]; a3 += (float)v[3];
    rs += rsp[((size_t)sp*NHEAD + h)*NTOK + i];
  }
  float inv = 1.0f/rs;
  f32x4 o = (f32x4){a0*inv, a1*inv, a2*inv, a3*inv};
  *(f32x4*)(Xh + (((size_t)h*NTOK + i)*DKH) + d4*4) = o;
}

// ---------------- LN with the faithful scrambled reshape + residual ----------------
__global__ __launch_bounds__(256) void k_ln0(const float* __restrict__ Xh, const float* __restrict__ resid,
        const float* __restrict__ g, const float* __restrict__ b, float* __restrict__ out0){
  const int n = blockIdx.x, t = threadIdx.x;
  const int h = n >> 7, dk = (n >> 1) & 63, mo = (n & 1)*512;
  float x0 = Xh[((size_t)h*NTOK + mo + t)*DKH + dk]       + resid[(size_t)n*DMODEL + t];
  float x1 = Xh[((size_t)h*NTOK + mo + t + 256)*DKH + dk] + resid[(size_t)n*DMODEL + t + 256];
  __shared__ float red[8];
  float s = wave_sum_f(x0 + x1);
  float q = wave_sum_f(x0*x0 + x1*x1);
  int wid = t >> 6, lane = t & 63;
  if (lane == 0){ red[wid] = s; red[4+wid] = q; }
  __syncthreads();
  float S = red[0]+red[1]+red[2]+red[3];
  float Q = red[4]+red[5]+red[6]+red[7];
  float mean = S * (1.0f/512.0f);
  float var = Q * (1.0f/512.0f) - mean*mean;
  float rs = rsqrtf(var + 1e-5f);
  out0[(size_t)n*DMODEL + t]       = (x0-mean)*rs*g[t] + b[t];
  out0[(size_t)n*DMODEL + t + 256] = (x1-mean)*rs*g[t+256] + b[t+256];
}

__global__ __launch_bounds__(256) void k_lnf(const float* __restrict__ x, const float* __restrict__ g,
        const float* __restrict__ b, float* __restrict__ out){
  const int n = blockIdx.x, t = threadIdx.x;
  float x0 = x[(size_t)n*DMODEL + t];
  float x1 = x[(size_t)n*DMODEL + t + 256];
  __shared__ float red[8];
  float s = wave_sum_f(x0 + x1);
  float q = wave_sum_f(x0*x0 + x1*x1);
  int wid = t >> 6, lane = t & 63;
  if (lane == 0){ red[wid] = s; red[4+wid] = q; }
  __syncthreads();
  float S = red[0]+red[1]+red[2]+red[3];
  float Q = red[4]+red[5]+red[6]+red[7];
  float mean = S * (1.0f/512.0f);
  float var = Q * (1.0f/512.0f) - mean*mean;
  float rs = rsqrtf(var + 1e-5f);
  out[(size_t)n*DMODEL + t]       = (x0-mean)*rs*g[t] + b[t];
  out[(size_t)n*DMODEL + t + 256] = (x1-mean)*rs*g[t+256] + b[t+256];
}

extern "C" void kernel_launch(void* const* d_in, const int* in_sizes, int n_in,
                              void* d_out, int out_size, void* d_ws, size_t ws_size,
                              hipStream_t stream){
  (void)in_sizes; (void)n_in; (void)out_size; (void)ws_size;
  const float* in_q = (const float*)d_in[0];
  const float* in_k = (const float*)d_in[1];
  const float* in_v = (const float*)d_in[2];
  const float* box  = (const float*)d_in[3];
  const float* Wq   = (const float*)d_in[4];
  const float* bq   = (const float*)d_in[5];
  const float* Wk   = (const float*)d_in[6];
  const float* bk   = (const float*)d_in[7];
  const float* Wv   = (const float*)d_in[8];
  const float* bv   = (const float*)d_in[9];
  const float* Wo   = (const float*)d_in[10];
  const float* bo   = (const float*)d_in[11];
  const float* WGw  = (const float*)d_in[12];
  const float* WGb  = (const float*)d_in[13];
  const float* ln0g = (const float*)d_in[14];
  const float* ln0b = (const float*)d_in[15];
  const float* lng  = (const float*)d_in[16];
  const float* lnb  = (const float*)d_in[17];

  float* ws = (float*)d_ws;
  // ws layout (float offsets); lifetimes overlaid to stay <= 41.1 MB:
  float*    bx   = ws;                               // [0, 8192)
  ushort_t* Qb   = (ushort_t*)(ws + 8192);           // 524288 ushorts
  ushort_t* Kb   = Qb + 524288;
  ushort_t* Vt   = Kb + 524288;                      // ends at float-offset 794624
  ushort_t* Xpb  = (ushort_t*)(ws + 794624);         // [4][8][1024][64] bf16 = 1048576 floats
  float*    rsp  = ws + 1843200;                     // [4][8][1024]
  float*    glog = ws + 1875968;                     // 8M floats, ends 10264576 (41.1 MB)
  float*    Xh   = glog;                             // overlay: glog dead after k_attn2
  float*    out0 = ws + 8192;                        // overlay: Qb/Kb dead after k_attn2
  float*    tmp  = ws + 532480;                      // overlay: Vt/Xpb dead after k_combine
  float*    out  = (float*)d_out;

  k_box<<<dim3(4), dim3(256), 0, stream>>>(box, bx);
  k_gate<<<dim3(4096), dim3(256), 0, stream>>>(bx, WGw, WGb, glog);
  k_gemm_qkv_b<<<dim3(8,16,3), dim3(256), 0, stream>>>(in_q, in_k, in_v,
            Wq, Wk, Wv, bq, bk, bv, Qb, Kb, Vt);
  k_attn2<<<dim3(512), dim3(256), 0, stream>>>(Qb, Kb, Vt, glog, Xpb, rsp);
  k_combine<<<dim3(512), dim3(256), 0, stream>>>(Xpb, rsp, Xh);
  k_ln0<<<dim3(1024), dim3(256), 0, stream>>>(Xh, in_q, ln0g, ln0b, out0);
  k_gemm_o<<<dim3(8,16), dim3(256), 0, stream>>>(out0, Wo, bo, out0, tmp);
  k_lnf<<<dim3(1024), dim3(256), 0, stream>>>(tmp, lng, lnb, out);
}

// Round 3
// 104.014 us; speedup vs baseline: 1.8748x; 1.4312x over previous
//
#include <hip/hip_runtime.h>
#include <cstddef>

#define NTOK 1024
#define DMODEL 512
#define NHEAD 8
#define DKH 64
#define NSPLIT 4

typedef __attribute__((ext_vector_type(4))) float f32x4;
typedef __attribute__((ext_vector_type(8))) __bf16 bf16x8;
typedef __attribute__((ext_vector_type(4))) __bf16 bf16x4;
typedef __attribute__((ext_vector_type(4))) unsigned short u16x4;
typedef __attribute__((ext_vector_type(4))) _Float16 f16x4;
typedef unsigned short ushort_t;

__device__ __forceinline__ float wave_sum_f(float v){
  #pragma unroll
  for (int m=1; m<64; m<<=1) v += __shfl_xor(v, m, 64);
  return v;
}

__device__ __forceinline__ unsigned short f2bf(float f){
  __bf16 b = (__bf16)f;
  return __builtin_bit_cast(unsigned short, b);
}

// ---------------- box prep: cx, cy, w, h, log w, log h ----------------
__global__ void k_box(const float* __restrict__ box, float* __restrict__ bx){
  int i = blockIdx.x*blockDim.x + threadIdx.x;
  if (i >= NTOK) return;
  float xmin = box[i*4+0], ymin = box[i*4+1], xmax = box[i*4+2], ymax = box[i*4+3];
  float cx = (xmin+xmax)*0.5f, cy = (ymin+ymax)*0.5f;
  float w = xmax-xmin+1.0f, h = ymax-ymin+1.0f;
  bx[i] = cx; bx[NTOK+i] = cy; bx[2*NTOK+i] = w; bx[3*NTOK+i] = h;
  bx[4*NTOK+i] = __logf(w); bx[5*NTOK+i] = __logf(h);
}

// ---------------- convert fp32 inputs + weights -> bf16 ----------------
__global__ __launch_bounds__(256) void k_cvt(
    const float* __restrict__ q, const float* __restrict__ k, const float* __restrict__ v,
    const float* __restrict__ wq, const float* __restrict__ wk, const float* __restrict__ wv,
    const float* __restrict__ wo,
    ushort_t* __restrict__ qb, ushort_t* __restrict__ kb, ushort_t* __restrict__ vb,
    ushort_t* __restrict__ wqb, ushort_t* __restrict__ wkb, ushort_t* __restrict__ wvb,
    ushort_t* __restrict__ wob){
  int gi = blockIdx.x*256 + threadIdx.x;   // 8-elem group index, 327680 total
  const float* s; ushort_t* d; int off;
  if (gi < 196608){
    int seg = gi >> 16;
    off = (gi & 65535)*8;
    s = seg==0 ? q : seg==1 ? k : v;
    d = seg==0 ? qb : seg==1 ? kb : vb;
  } else {
    int g2 = gi - 196608;
    int seg = g2 >> 15;
    off = (g2 & 32767)*8;
    s = seg==0 ? wq : seg==1 ? wk : seg==2 ? wv : wo;
    d = seg==0 ? wqb : seg==1 ? wkb : seg==2 ? wvb : wob;
  }
  float4 a = *(const float4*)(s + off);
  float4 b = *(const float4*)(s + off + 4);
  u16x4 o0, o1;
  o0[0]=f2bf(a.x); o0[1]=f2bf(a.y); o0[2]=f2bf(a.z); o0[3]=f2bf(a.w);
  o1[0]=f2bf(b.x); o1[1]=f2bf(b.y); o1[2]=f2bf(b.z); o1[3]=f2bf(b.w);
  *(u16x4*)(d + off) = o0;
  *(u16x4*)(d + off + 4) = o1;
}

// ---------------- gating: glog[h][i][j] = log(clip(relu(emb . WGw + WGb), 1e-6)) -> fp16 ----------------
__global__ __launch_bounds__(256) void k_gate(const float* __restrict__ bx,
        const float* __restrict__ WGw, const float* __restrict__ WGb,
        _Float16* __restrict__ glog){
  const int t = threadIdx.x;
  const int j = (blockIdx.x & 15)*64 + (t & 63);
  const int i = (blockIdx.x >> 4)*4 + (t >> 6);
  const float* cx = bx;
  const float* cy = bx + NTOK;
  const float* ww = bx + 2*NTOK;
  const float* hh = bx + 3*NTOK;
  const float* lw = bx + 4*NTOK;
  const float* lh = bx + 5*NTOK;
  float cxi = cx[i], cyi = cy[i];
  float rwi = 1.0f/ww[i], rhi = 1.0f/hh[i];
  float dx = __logf(fmaxf(fabsf((cxi - cx[j])*rwi), 1e-3f));
  float dy = __logf(fmaxf(fabsf((cyi - cy[j])*rhi), 1e-3f));
  float dw = lw[i] - lw[j];
  float dh = lh[i] - lh[j];
  const float DM[8] = {100.0f, 42.16965f, 17.782794f, 7.4989421f,
                       3.1622777f, 1.3335214f, 0.56234133f, 0.23713737f};
  float pos[4] = {dx, dy, dw, dh};
  float sv[32], cv[32];
  #pragma unroll
  for (int p=0; p<4; p++){
    #pragma unroll
    for (int d=0; d<8; d++){
      float ang = pos[p]*DM[d];
      __sincosf(ang, &sv[p*8+d], &cv[p*8+d]);
    }
  }
  #pragma unroll
  for (int h=0; h<8; h++){
    float gd = WGb[h];
    #pragma unroll
    for (int a=0; a<32; a++)
      gd = fmaf(sv[a], WGw[h*64+a], fmaf(cv[a], WGw[h*64+32+a], gd));
    glog[((size_t)h<<20) + ((size_t)i<<10) + j] = (_Float16)__logf(fmaxf(gd, 1e-6f));
  }
}

// ---------------- MFMA QKV projection ----------------
// 128-thread blocks (2 waves), wave tile 32x32, K=512 fully unrolled, no LDS.
// z<2 (Q,K): acc = mfma(Wrows, Arows) -> row-major C[m][n], contiguous 8B stores.
// z==2 (V):  acc = mfma(Arows, Wrows) -> Vt[h][dk][j], contiguous 8B stores.
__global__ __launch_bounds__(128) void k_mm_qkv(
    const ushort_t* __restrict__ Aq, const ushort_t* __restrict__ Ak, const ushort_t* __restrict__ Av,
    const ushort_t* __restrict__ Wqb, const ushort_t* __restrict__ Wkb, const ushort_t* __restrict__ Wvb,
    const float* __restrict__ bq, const float* __restrict__ bk, const float* __restrict__ bv,
    ushort_t* __restrict__ Qb, ushort_t* __restrict__ Kb, ushort_t* __restrict__ Vt){
  const int z = blockIdx.z;
  const ushort_t* A = z==0 ? Aq : z==1 ? Ak : Av;
  const ushort_t* W = z==0 ? Wqb : z==1 ? Wkb : Wvb;
  const float* bias = z==0 ? bq : z==1 ? bk : bv;
  const int t = threadIdx.x, lane = t & 63, w = t >> 6;
  const int li = lane & 15, g = lane >> 4;
  const int m0 = blockIdx.y*32;
  const int n0 = blockIdx.x*64 + w*32;
  const ushort_t* ar = A + (size_t)(m0+li)*DMODEL + g*8;
  const ushort_t* wr = W + (size_t)(n0+li)*DMODEL + g*8;
  f32x4 acc[2][2] = {};
  if (z < 2){
    #pragma unroll
    for (int k0=0; k0<DMODEL; k0+=64){
      bf16x8 wf0a = *(const bf16x8*)(wr + k0);
      bf16x8 wf0b = *(const bf16x8*)(wr + k0 + 32);
      bf16x8 wf1a = *(const bf16x8*)(wr + 16*DMODEL + k0);
      bf16x8 wf1b = *(const bf16x8*)(wr + 16*DMODEL + k0 + 32);
      bf16x8 af0a = *(const bf16x8*)(ar + k0);
      bf16x8 af0b = *(const bf16x8*)(ar + k0 + 32);
      bf16x8 af1a = *(const bf16x8*)(ar + 16*DMODEL + k0);
      bf16x8 af1b = *(const bf16x8*)(ar + 16*DMODEL + k0 + 32);
      acc[0][0] = __builtin_amdgcn_mfma_f32_16x16x32_bf16(wf0a, af0a, acc[0][0], 0,0,0);
      acc[0][0] = __builtin_amdgcn_mfma_f32_16x16x32_bf16(wf0b, af0b, acc[0][0], 0,0,0);
      acc[0][1] = __builtin_amdgcn_mfma_f32_16x16x32_bf16(wf0a, af1a, acc[0][1], 0,0,0);
      acc[0][1] = __builtin_amdgcn_mfma_f32_16x16x32_bf16(wf0b, af1b, acc[0][1], 0,0,0);
      acc[1][0] = __builtin_amdgcn_mfma_f32_16x16x32_bf16(wf1a, af0a, acc[1][0], 0,0,0);
      acc[1][0] = __builtin_amdgcn_mfma_f32_16x16x32_bf16(wf1b, af0b, acc[1][0], 0,0,0);
      acc[1][1] = __builtin_amdgcn_mfma_f32_16x16x32_bf16(wf1a, af1a, acc[1][1], 0,0,0);
      acc[1][1] = __builtin_amdgcn_mfma_f32_16x16x32_bf16(wf1b, af1b, acc[1][1], 0,0,0);
    }
    ushort_t* C = z ? Kb : Qb;
    #pragma unroll
    for (int nf=0; nf<2; nf++){
      int n = n0 + nf*16 + g*4;
      float4 b4 = *(const float4*)(bias + n);
      const float* bp = (const float*)&b4;
      #pragma unroll
      for (int mf=0; mf<2; mf++){
        int m = m0 + mf*16 + li;
        u16x4 o;
        #pragma unroll
        for (int r=0; r<4; r++) o[r] = f2bf(acc[nf][mf][r] + bp[r]);
        *(u16x4*)(C + (size_t)m*DMODEL + n) = o;
      }
    }
  } else {
    #pragma unroll
    for (int k0=0; k0<DMODEL; k0+=64){
      bf16x8 wf0a = *(const bf16x8*)(wr + k0);
      bf16x8 wf0b = *(const bf16x8*)(wr + k0 + 32);
      bf16x8 wf1a = *(const bf16x8*)(wr + 16*DMODEL + k0);
      bf16x8 wf1b = *(const bf16x8*)(wr + 16*DMODEL + k0 + 32);
      bf16x8 af0a = *(const bf16x8*)(ar + k0);
      bf16x8 af0b = *(const bf16x8*)(ar + k0 + 32);
      bf16x8 af1a = *(const bf16x8*)(ar + 16*DMODEL + k0);
      bf16x8 af1b = *(const bf16x8*)(ar + 16*DMODEL + k0 + 32);
      acc[0][0] = __builtin_amdgcn_mfma_f32_16x16x32_bf16(af0a, wf0a, acc[0][0], 0,0,0);
      acc[0][0] = __builtin_amdgcn_mfma_f32_16x16x32_bf16(af0b, wf0b, acc[0][0], 0,0,0);
      acc[0][1] = __builtin_amdgcn_mfma_f32_16x16x32_bf16(af0a, wf1a, acc[0][1], 0,0,0);
      acc[0][1] = __builtin_amdgcn_mfma_f32_16x16x32_bf16(af0b, wf1b, acc[0][1], 0,0,0);
      acc[1][0] = __builtin_amdgcn_mfma_f32_16x16x32_bf16(af1a, wf0a, acc[1][0], 0,0,0);
      acc[1][0] = __builtin_amdgcn_mfma_f32_16x16x32_bf16(af1b, wf0b, acc[1][0], 0,0,0);
      acc[1][1] = __builtin_amdgcn_mfma_f32_16x16x32_bf16(af1a, wf1a, acc[1][1], 0,0,0);
      acc[1][1] = __builtin_amdgcn_mfma_f32_16x16x32_bf16(af1b, wf1b, acc[1][1], 0,0,0);
    }
    #pragma unroll
    for (int mf=0; mf<2; mf++){
      int m = m0 + mf*16 + g*4;
      #pragma unroll
      for (int nf=0; nf<2; nf++){
        int n = n0 + nf*16 + li;
        float bn = bias[n];
        u16x4 o;
        #pragma unroll
        for (int r=0; r<4; r++) o[r] = f2bf(acc[mf][nf][r] + bn);
        *(u16x4*)(Vt + (((size_t)(n>>6))<<16) + ((size_t)(n&63)<<10) + m) = o;
      }
    }
  }
}

// ---------------- MFMA O-projection: C = A@W^T + bias + add (fp32 out) ----------------
__global__ __launch_bounds__(128) void k_mm_o(
    const ushort_t* __restrict__ A, const ushort_t* __restrict__ W,
    const float* __restrict__ bias, const float* __restrict__ add, float* __restrict__ C){
  const int t = threadIdx.x, lane = t & 63, w = t >> 6;
  const int li = lane & 15, g = lane >> 4;
  const int m0 = blockIdx.y*32;
  const int n0 = blockIdx.x*64 + w*32;
  const ushort_t* ar = A + (size_t)(m0+li)*DMODEL + g*8;
  const ushort_t* wr = W + (size_t)(n0+li)*DMODEL + g*8;
  f32x4 acc[2][2] = {};
  #pragma unroll
  for (int k0=0; k0<DMODEL; k0+=64){
    bf16x8 wf0a = *(const bf16x8*)(wr + k0);
    bf16x8 wf0b = *(const bf16x8*)(wr + k0 + 32);
    bf16x8 wf1a = *(const bf16x8*)(wr + 16*DMODEL + k0);
    bf16x8 wf1b = *(const bf16x8*)(wr + 16*DMODEL + k0 + 32);
    bf16x8 af0a = *(const bf16x8*)(ar + k0);
    bf16x8 af0b = *(const bf16x8*)(ar + k0 + 32);
    bf16x8 af1a = *(const bf16x8*)(ar + 16*DMODEL + k0);
    bf16x8 af1b = *(const bf16x8*)(ar + 16*DMODEL + k0 + 32);
    acc[0][0] = __builtin_amdgcn_mfma_f32_16x16x32_bf16(wf0a, af0a, acc[0][0], 0,0,0);
    acc[0][0] = __builtin_amdgcn_mfma_f32_16x16x32_bf16(wf0b, af0b, acc[0][0], 0,0,0);
    acc[0][1] = __builtin_amdgcn_mfma_f32_16x16x32_bf16(wf0a, af1a, acc[0][1], 0,0,0);
    acc[0][1] = __builtin_amdgcn_mfma_f32_16x16x32_bf16(wf0b, af1b, acc[0][1], 0,0,0);
    acc[1][0] = __builtin_amdgcn_mfma_f32_16x16x32_bf16(wf1a, af0a, acc[1][0], 0,0,0);
    acc[1][0] = __builtin_amdgcn_mfma_f32_16x16x32_bf16(wf1b, af0b, acc[1][0], 0,0,0);
    acc[1][1] = __builtin_amdgcn_mfma_f32_16x16x32_bf16(wf1a, af1a, acc[1][1], 0,0,0);
    acc[1][1] = __builtin_amdgcn_mfma_f32_16x16x32_bf16(wf1b, af1b, acc[1][1], 0,0,0);
  }
  #pragma unroll
  for (int nf=0; nf<2; nf++){
    int n = n0 + nf*16 + g*4;
    float4 b4 = *(const float4*)(bias + n);
    const float* bp = (const float*)&b4;
    #pragma unroll
    for (int mf=0; mf<2; mf++){
      int m = m0 + mf*16 + li;
      float4 ad = *(const float4*)(add + (size_t)m*DMODEL + n);
      const float* ap = (const float*)&ad;
      f32x4 o;
      #pragma unroll
      for (int r=0; r<4; r++) o[r] = acc[nf][mf][r] + bp[r] + ap[r];
      *(f32x4*)(C + (size_t)m*DMODEL + n) = o;
    }
  }
}

// ---------------- MFMA attention (unchanged structure; glog now fp16) ----------------
__global__ __launch_bounds__(256) void k_attn2(const ushort_t* __restrict__ Qb,
     const ushort_t* __restrict__ Kb, const ushort_t* __restrict__ Vt,
     const _Float16* __restrict__ glog, ushort_t* __restrict__ Xpb, float* __restrict__ rsp){
  const int t = threadIdx.x;
  const int lane = t & 63;
  const int w = t >> 6;
  const int id = blockIdx.x*4 + w;
  const int it = id & 63;
  const int h  = (id >> 6) & 7;
  const int sp = id >> 9;
  const int i0 = it*16;
  const int li = lane & 15, g = lane >> 4;

  const ushort_t* qp = Qb + (size_t)(i0+li)*DMODEL + h*DKH + g*8;
  bf16x8 qf0 = *(const bf16x8*)(qp);
  bf16x8 qf1 = *(const bf16x8*)(qp + 32);

  f32x4 xacc[4];
  #pragma unroll
  for (int mf=0; mf<4; mf++) xacc[mf] = (f32x4){0.f,0.f,0.f,0.f};
  float rsum = 0.f;

  const ushort_t*  kbase = Kb + (size_t)li*DMODEL + h*DKH + g*8;
  const _Float16*  gbase = glog + ((size_t)h<<20) + ((size_t)(i0+li)<<10) + g*4;
  const ushort_t*  vbase = Vt + ((size_t)h<<16) + (size_t)li*NTOK + g*4;

  const int jbeg = sp*(NTOK/NSPLIT), jend = jbeg + NTOK/NSPLIT;
  for (int j0 = jbeg; j0 < jend; j0 += 32){
    const ushort_t* kp = kbase + (size_t)j0*DMODEL;
    bf16x8 a00 = *(const bf16x8*)(kp);
    bf16x8 a01 = *(const bf16x8*)(kp + 32);
    bf16x8 a10 = *(const bf16x8*)(kp + 16*DMODEL);
    bf16x8 a11 = *(const bf16x8*)(kp + 16*DMODEL + 32);
    f32x4 s0 = (f32x4){0.f,0.f,0.f,0.f};
    f32x4 s1 = (f32x4){0.f,0.f,0.f,0.f};
    s0 = __builtin_amdgcn_mfma_f32_16x16x32_bf16(a00, qf0, s0, 0,0,0);
    s0 = __builtin_amdgcn_mfma_f32_16x16x32_bf16(a01, qf1, s0, 0,0,0);
    s1 = __builtin_amdgcn_mfma_f32_16x16x32_bf16(a10, qf0, s1, 0,0,0);
    s1 = __builtin_amdgcn_mfma_f32_16x16x32_bf16(a11, qf1, s1, 0,0,0);
    f16x4 g0 = *(const f16x4*)(gbase + j0);
    f16x4 g1 = *(const f16x4*)(gbase + j0 + 16);
    float p[8];
    #pragma unroll
    for (int r=0; r<4; r++){ p[r]   = __expf((float)g0[r] + s0[r]*0.125f); rsum += p[r]; }
    #pragma unroll
    for (int r=0; r<4; r++){ p[4+r] = __expf((float)g1[r] + s1[r]*0.125f); rsum += p[4+r]; }
    bf16x8 pb;
    pb[0]=(__bf16)p[0]; pb[1]=(__bf16)p[1]; pb[2]=(__bf16)p[2]; pb[3]=(__bf16)p[3];
    pb[4]=(__bf16)p[4]; pb[5]=(__bf16)p[5]; pb[6]=(__bf16)p[6]; pb[7]=(__bf16)p[7];
    #pragma unroll
    for (int mf=0; mf<4; mf++){
      const ushort_t* vp = vbase + (size_t)mf*16*NTOK + j0;
      bf16x4 lo = *(const bf16x4*)(vp);
      bf16x4 hi = *(const bf16x4*)(vp + 16);
      bf16x8 vf = __builtin_shufflevector(lo, hi, 0,1,2,3,4,5,6,7);
      xacc[mf] = __builtin_amdgcn_mfma_f32_16x16x32_bf16(vf, pb, xacc[mf], 0,0,0);
    }
  }
  rsum += __shfl_xor(rsum, 16, 64);
  rsum += __shfl_xor(rsum, 32, 64);
  if (lane < 16) rsp[((size_t)sp*NHEAD + h)*NTOK + i0 + li] = rsum;
  ushort_t* xp = Xpb + ((((size_t)sp*NHEAD + h)*NTOK) + i0 + li)*DKH + g*4;
  #pragma unroll
  for (int mf=0; mf<4; mf++){
    u16x4 o;
    #pragma unroll
    for (int r=0; r<4; r++) o[r] = f2bf(xacc[mf][r]);
    *(u16x4*)(xp + mf*16) = o;
  }
}

// combine j-split partials: Xh[h][i][d] = sum_sp Xp / sum_sp rs
__global__ __launch_bounds__(256) void k_combine(const ushort_t* __restrict__ Xpb,
        const float* __restrict__ rsp, float* __restrict__ Xh){
  int gid = blockIdx.x*256 + threadIdx.x;
  int d4 = gid & 15;
  int i  = (gid >> 4) & 1023;
  int h  = gid >> 14;
  float a0=0.f, a1=0.f, a2=0.f, a3=0.f, rs=0.f;
  #pragma unroll
  for (int sp=0; sp<NSPLIT; sp++){
    const ushort_t* p = Xpb + ((((size_t)sp*NHEAD + h)*NTOK) + i)*DKH + d4*4;
    bf16x4 v = *(const bf16x4*)p;
    a0 += (float)v[0]; a1 += (float)v[1]; a2 += (float)v[2]; a3 += (float)v[3];
    rs += rsp[((size_t)sp*NHEAD + h)*NTOK + i];
  }
  float inv = 1.0f/rs;
  f32x4 o = (f32x4){a0*inv, a1*inv, a2*inv, a3*inv};
  *(f32x4*)(Xh + (((size_t)h*NTOK + i)*DKH) + d4*4) = o;
}

// ---------------- LN with the faithful scrambled reshape + residual ----------------
// also emits bf16 copy for the O-projection MFMA A-operand
__global__ __launch_bounds__(256) void k_ln0(const float* __restrict__ Xh, const float* __restrict__ resid,
        const float* __restrict__ g, const float* __restrict__ b,
        float* __restrict__ out0, ushort_t* __restrict__ out0b){
  const int n = blockIdx.x, t = threadIdx.x;
  const int h = n >> 7, dk = (n >> 1) & 63, mo = (n & 1)*512;
  float x0 = Xh[((size_t)h*NTOK + mo + t)*DKH + dk]       + resid[(size_t)n*DMODEL + t];
  float x1 = Xh[((size_t)h*NTOK + mo + t + 256)*DKH + dk] + resid[(size_t)n*DMODEL + t + 256];
  __shared__ float red[8];
  float s = wave_sum_f(x0 + x1);
  float q = wave_sum_f(x0*x0 + x1*x1);
  int wid = t >> 6, lane = t & 63;
  if (lane == 0){ red[wid] = s; red[4+wid] = q; }
  __syncthreads();
  float S = red[0]+red[1]+red[2]+red[3];
  float Q = red[4]+red[5]+red[6]+red[7];
  float mean = S * (1.0f/512.0f);
  float var = Q * (1.0f/512.0f) - mean*mean;
  float rs = rsqrtf(var + 1e-5f);
  float y0 = (x0-mean)*rs*g[t] + b[t];
  float y1 = (x1-mean)*rs*g[t+256] + b[t+256];
  out0[(size_t)n*DMODEL + t]        = y0;
  out0[(size_t)n*DMODEL + t + 256]  = y1;
  out0b[(size_t)n*DMODEL + t]       = f2bf(y0);
  out0b[(size_t)n*DMODEL + t + 256] = f2bf(y1);
}

__global__ __launch_bounds__(256) void k_lnf(const float* __restrict__ x, const float* __restrict__ g,
        const float* __restrict__ b, float* __restrict__ out){
  const int n = blockIdx.x, t = threadIdx.x;
  float x0 = x[(size_t)n*DMODEL + t];
  float x1 = x[(size_t)n*DMODEL + t + 256];
  __shared__ float red[8];
  float s = wave_sum_f(x0 + x1);
  float q = wave_sum_f(x0*x0 + x1*x1);
  int wid = t >> 6, lane = t & 63;
  if (lane == 0){ red[wid] = s; red[4+wid] = q; }
  __syncthreads();
  float S = red[0]+red[1]+red[2]+red[3];
  float Q = red[4]+red[5]+red[6]+red[7];
  float mean = S * (1.0f/512.0f);
  float var = Q * (1.0f/512.0f) - mean*mean;
  float rs = rsqrtf(var + 1e-5f);
  out[(size_t)n*DMODEL + t]       = (x0-mean)*rs*g[t] + b[t];
  out[(size_t)n*DMODEL + t + 256] = (x1-mean)*rs*g[t+256] + b[t+256];
}

extern "C" void kernel_launch(void* const* d_in, const int* in_sizes, int n_in,
                              void* d_out, int out_size, void* d_ws, size_t ws_size,
                              hipStream_t stream){
  (void)in_sizes; (void)n_in; (void)out_size; (void)ws_size;
  const float* in_q = (const float*)d_in[0];
  const float* in_k = (const float*)d_in[1];
  const float* in_v = (const float*)d_in[2];
  const float* box  = (const float*)d_in[3];
  const float* Wq   = (const float*)d_in[4];
  const float* bq   = (const float*)d_in[5];
  const float* Wk   = (const float*)d_in[6];
  const float* bk   = (const float*)d_in[7];
  const float* Wv   = (const float*)d_in[8];
  const float* bv   = (const float*)d_in[9];
  const float* Wo   = (const float*)d_in[10];
  const float* bo   = (const float*)d_in[11];
  const float* WGw  = (const float*)d_in[12];
  const float* WGb  = (const float*)d_in[13];
  const float* ln0g = (const float*)d_in[14];
  const float* ln0b = (const float*)d_in[15];
  const float* lng  = (const float*)d_in[16];
  const float* lnb  = (const float*)d_in[17];

  float* ws = (float*)d_ws;
  // ---- ws layout (float-offset units) ----
  float*    bx   = ws;                              // [0, 8192)
  ushort_t* Qb   = (ushort_t*)(ws + 8192);          // [8192, 270336)
  ushort_t* Kb   = (ushort_t*)(ws + 270336);        // [270336, 532480)
  ushort_t* Vt   = (ushort_t*)(ws + 532480);        // [532480, 794624)
  ushort_t* Abq  = (ushort_t*)(ws + 794624);        // [794624, 1056768)
  ushort_t* Abk  = (ushort_t*)(ws + 1056768);       // [1056768, 1318912)
  ushort_t* Abv  = (ushort_t*)(ws + 1318912);       // [1318912, 1581056)
  ushort_t* Wqb  = (ushort_t*)(ws + 1581056);       // [1581056, 1712128)
  ushort_t* Wkb  = (ushort_t*)(ws + 1712128);       // [1712128, 1843200)
  ushort_t* Wvb  = (ushort_t*)(ws + 1843200);       // [1843200, 1974272)
  ushort_t* Wob  = (ushort_t*)(ws + 1974272);       // [1974272, 2105344)
  ushort_t* Xpb  = (ushort_t*)(ws + 2105344);       // [2105344, 3153920)
  float*    rsp  = ws + 3153920;                    // [3153920, 3186688)
  _Float16* glog = (_Float16*)(ws + 3186688);       // [3186688, 7380992)  (16 MB fp16)
  // overlays (lifetimes disjoint):
  float*    Xh   = ws + 3186688;                    // over glog (dead after k_attn2)
  float*    out0 = ws + 794624;                     // over Abq/Abk (dead after k_mm_qkv)
  ushort_t* out0b= (ushort_t*)(ws + 1318912);       // over Abv (dead after k_mm_qkv)
  float*    tmp  = ws + 2105344;                    // over Xpb (dead after k_combine)
  float*    out  = (float*)d_out;

  k_box<<<dim3(4), dim3(256), 0, stream>>>(box, bx);
  k_cvt<<<dim3(1280), dim3(256), 0, stream>>>(in_q, in_k, in_v, Wq, Wk, Wv, Wo,
            Abq, Abk, Abv, Wqb, Wkb, Wvb, Wob);
  k_gate<<<dim3(4096), dim3(256), 0, stream>>>(bx, WGw, WGb, glog);
  k_mm_qkv<<<dim3(8,32,3), dim3(128), 0, stream>>>(Abq, Abk, Abv, Wqb, Wkb, Wvb,
            bq, bk, bv, Qb, Kb, Vt);
  k_attn2<<<dim3(512), dim3(256), 0, stream>>>(Qb, Kb, Vt, glog, Xpb, rsp);
  k_combine<<<dim3(512), dim3(256), 0, stream>>>(Xpb, rsp, Xh);
  k_ln0<<<dim3(1024), dim3(256), 0, stream>>>(Xh, in_q, ln0g, ln0b, out0, out0b);
  k_mm_o<<<dim3(8,32), dim3(128), 0, stream>>>(out0b, Wob, bo, out0, tmp);
  k_lnf<<<dim3(1024), dim3(256), 0, stream>>>(tmp, lng, lnb, out);
}

// Round 4
// 90.796 us; speedup vs baseline: 2.1478x; 1.1456x over previous
//
#include <hip/hip_runtime.h>
#include <cstddef>

#define NTOK 1024
#define DMODEL 512
#define NHEAD 8
#define DKH 64
#define NSPLIT 4

typedef __attribute__((ext_vector_type(4))) float f32x4;
typedef __attribute__((ext_vector_type(8))) __bf16 bf16x8;
typedef __attribute__((ext_vector_type(4))) __bf16 bf16x4;
typedef __attribute__((ext_vector_type(4))) unsigned short u16x4;
typedef __attribute__((ext_vector_type(8))) unsigned short u16x8;
typedef __attribute__((ext_vector_type(4))) _Float16 f16x4;
typedef unsigned short ushort_t;

__device__ __forceinline__ float wave_sum_f(float v){
  #pragma unroll
  for (int m=1; m<64; m<<=1) v += __shfl_xor(v, m, 64);
  return v;
}
__device__ __forceinline__ unsigned short f2bf(float f){
  __bf16 b = (__bf16)f;
  return __builtin_bit_cast(unsigned short, b);
}
__device__ __forceinline__ float bf2f(unsigned short u){
  return (float)__builtin_bit_cast(__bf16, u);
}

// ================= k_pre: fused [gate-MFMA (blocks 0..1023)] + [fp32->bf16 cvt (blocks 1024..2303)] ====
// Gate: wg16[h][i][j] = max(relu(emb(i,j).WGw[h] + WGb[h]), 6.1e-5) in fp16.
// NO log: softmax identity exp(log(clip(wg))+s) == clip(wg)*exp(s); clip raised to fp16-normal min,
// which is exactly-equivalent after normalization when a whole row clips, negligible otherwise.
// Head-dot via MFMA: A-frag rows = 16 j's (lane computes 8 sin + 8 cos of pos-component g),
// B-frag cols = 8 heads (WGw), out[j][h] accumulated over K=32 sin + K=32 cos.
__global__ __launch_bounds__(256) void k_pre(
    const float* __restrict__ box, const float* __restrict__ WGw, const float* __restrict__ WGb,
    _Float16* __restrict__ wg16,
    const float* __restrict__ q, const float* __restrict__ k, const float* __restrict__ v,
    const float* __restrict__ wq, const float* __restrict__ wk, const float* __restrict__ wv,
    const float* __restrict__ wo,
    ushort_t* __restrict__ qb, ushort_t* __restrict__ kb, ushort_t* __restrict__ vb,
    ushort_t* __restrict__ wqb, ushort_t* __restrict__ wkb, ushort_t* __restrict__ wvb,
    ushort_t* __restrict__ wob){
  const int t = threadIdx.x;
  if (blockIdx.x >= 1024){
    // ---- cvt blocks ----
    int gi = (blockIdx.x - 1024)*256 + t;   // 8-elem group index, 327680 total
    const float* s; ushort_t* d; int off;
    if (gi < 196608){
      int seg = gi >> 16;
      off = (gi & 65535)*8;
      s = seg==0 ? q : seg==1 ? k : v;
      d = seg==0 ? qb : seg==1 ? kb : vb;
    } else {
      int g2 = gi - 196608;
      int seg = g2 >> 15;
      off = (g2 & 32767)*8;
      s = seg==0 ? wq : seg==1 ? wk : seg==2 ? wv : wo;
      d = seg==0 ? wqb : seg==1 ? wkb : seg==2 ? wvb : wob;
    }
    float4 a = *(const float4*)(s + off);
    float4 b = *(const float4*)(s + off + 4);
    u16x4 o0, o1;
    o0[0]=f2bf(a.x); o0[1]=f2bf(a.y); o0[2]=f2bf(a.z); o0[3]=f2bf(a.w);
    o1[0]=f2bf(b.x); o1[1]=f2bf(b.y); o1[2]=f2bf(b.z); o1[3]=f2bf(b.w);
    *(u16x4*)(d + off) = o0;
    *(u16x4*)(d + off + 4) = o1;
    return;
  }
  // ---- gate blocks: one i per block, 4 waves x 256-j quarters ----
  __shared__ float arr[4][1024];   // cx, cy, lw, lh
  #pragma unroll
  for (int u=0; u<4; u++){
    int idx = u*256 + t;
    float4 b4 = *(const float4*)(box + idx*4);
    arr[0][idx] = (b4.x + b4.z)*0.5f;
    arr[1][idx] = (b4.y + b4.w)*0.5f;
    arr[2][idx] = __logf(b4.z - b4.x + 1.0f);
    arr[3][idx] = __logf(b4.w - b4.y + 1.0f);
  }
  const int i = blockIdx.x;
  const int lane = t & 63, w = t >> 6, li = lane & 15, g = lane >> 4;
  float4 bi = *(const float4*)(box + i*4);
  float wi = bi.z - bi.x + 1.0f, hi = bi.w - bi.y + 1.0f;
  float Pi = (g==0) ? (bi.x+bi.z)*0.5f : (g==1) ? (bi.y+bi.w)*0.5f
           : (g==2) ? __logf(wi) : __logf(hi);
  float Ri = (g==0) ? 1.0f/wi : (g==1) ? 1.0f/hi : 1.0f;
  const bool doLog = (g < 2);
  // B-frags: WGw sin-half and cos-half (cols = heads, zero for li>=8)
  bf16x8 wfs = {}, wfc = {};
  float wgb_li = 0.0f;
  if (li < 8){
    #pragma unroll
    for (int e=0; e<8; e++){
      wfs[e] = (__bf16)WGw[li*64 + g*8 + e];
      wfc[e] = (__bf16)WGw[li*64 + 32 + g*8 + e];
    }
    wgb_li = WGb[li];
  }
  __syncthreads();
  const float* parr = &arr[g][0];
  const float DM[8] = {100.0f, 42.16965f, 17.782794f, 7.4989421f,
                       3.1622777f, 1.3335214f, 0.56234133f, 0.23713737f};
  const int jbeg = w*256;
  for (int it=0; it<16; ++it){
    int j = jbeg + it*16 + li;
    float diff = (Pi - parr[j])*Ri;
    float lg = __logf(fmaxf(fabsf(diff), 1e-3f));
    float dv = doLog ? lg : diff;
    bf16x8 afs, afc;
    #pragma unroll
    for (int e=0; e<8; e++){
      float ang = dv * DM[e];
      afs[e] = (__bf16)__sinf(ang);
      afc[e] = (__bf16)__cosf(ang);
    }
    f32x4 acc = (f32x4){0.f,0.f,0.f,0.f};
    acc = __builtin_amdgcn_mfma_f32_16x16x32_bf16(afs, wfs, acc, 0,0,0);
    acc = __builtin_amdgcn_mfma_f32_16x16x32_bf16(afc, wfc, acc, 0,0,0);
    if (li < 8){
      // lane holds out[j = jbeg+it*16+g*4+r][h = li]
      f16x4 o;
      #pragma unroll
      for (int r=0; r<4; r++)
        o[r] = (_Float16)fmaxf(acc[r] + wgb_li, 6.103515625e-05f);
      *(f16x4*)(wg16 + (((size_t)li<<20) + ((size_t)i<<10) + jbeg + it*16 + g*4)) = o;
    }
  }
}

// ================= MFMA QKV projection (unchanged structure) =================
__global__ __launch_bounds__(128) void k_mm_qkv(
    const ushort_t* __restrict__ Aq, const ushort_t* __restrict__ Ak, const ushort_t* __restrict__ Av,
    const ushort_t* __restrict__ Wqb, const ushort_t* __restrict__ Wkb, const ushort_t* __restrict__ Wvb,
    const float* __restrict__ bq, const float* __restrict__ bk, const float* __restrict__ bv,
    ushort_t* __restrict__ Qb, ushort_t* __restrict__ Kb, ushort_t* __restrict__ Vt){
  const int z = blockIdx.z;
  const ushort_t* A = z==0 ? Aq : z==1 ? Ak : Av;
  const ushort_t* W = z==0 ? Wqb : z==1 ? Wkb : Wvb;
  const float* bias = z==0 ? bq : z==1 ? bk : bv;
  const int t = threadIdx.x, lane = t & 63, w = t >> 6;
  const int li = lane & 15, g = lane >> 4;
  const int m0 = blockIdx.y*32;
  const int n0 = blockIdx.x*64 + w*32;
  const ushort_t* ar = A + (size_t)(m0+li)*DMODEL + g*8;
  const ushort_t* wr = W + (size_t)(n0+li)*DMODEL + g*8;
  f32x4 acc[2][2] = {};
  if (z < 2){
    #pragma unroll
    for (int k0=0; k0<DMODEL; k0+=64){
      bf16x8 wf0a = *(const bf16x8*)(wr + k0);
      bf16x8 wf0b = *(const bf16x8*)(wr + k0 + 32);
      bf16x8 wf1a = *(const bf16x8*)(wr + 16*DMODEL + k0);
      bf16x8 wf1b = *(const bf16x8*)(wr + 16*DMODEL + k0 + 32);
      bf16x8 af0a = *(const bf16x8*)(ar + k0);
      bf16x8 af0b = *(const bf16x8*)(ar + k0 + 32);
      bf16x8 af1a = *(const bf16x8*)(ar + 16*DMODEL + k0);
      bf16x8 af1b = *(const bf16x8*)(ar + 16*DMODEL + k0 + 32);
      acc[0][0] = __builtin_amdgcn_mfma_f32_16x16x32_bf16(wf0a, af0a, acc[0][0], 0,0,0);
      acc[0][0] = __builtin_amdgcn_mfma_f32_16x16x32_bf16(wf0b, af0b, acc[0][0], 0,0,0);
      acc[0][1] = __builtin_amdgcn_mfma_f32_16x16x32_bf16(wf0a, af1a, acc[0][1], 0,0,0);
      acc[0][1] = __builtin_amdgcn_mfma_f32_16x16x32_bf16(wf0b, af1b, acc[0][1], 0,0,0);
      acc[1][0] = __builtin_amdgcn_mfma_f32_16x16x32_bf16(wf1a, af0a, acc[1][0], 0,0,0);
      acc[1][0] = __builtin_amdgcn_mfma_f32_16x16x32_bf16(wf1b, af0b, acc[1][0], 0,0,0);
      acc[1][1] = __builtin_amdgcn_mfma_f32_16x16x32_bf16(wf1a, af1a, acc[1][1], 0,0,0);
      acc[1][1] = __builtin_amdgcn_mfma_f32_16x16x32_bf16(wf1b, af1b, acc[1][1], 0,0,0);
    }
    ushort_t* C = z ? Kb : Qb;
    #pragma unroll
    for (int nf=0; nf<2; nf++){
      int n = n0 + nf*16 + g*4;
      float4 b4 = *(const float4*)(bias + n);
      const float* bp = (const float*)&b4;
      #pragma unroll
      for (int mf=0; mf<2; mf++){
        int m = m0 + mf*16 + li;
        u16x4 o;
        #pragma unroll
        for (int r=0; r<4; r++) o[r] = f2bf(acc[nf][mf][r] + bp[r]);
        *(u16x4*)(C + (size_t)m*DMODEL + n) = o;
      }
    }
  } else {
    #pragma unroll
    for (int k0=0; k0<DMODEL; k0+=64){
      bf16x8 wf0a = *(const bf16x8*)(wr + k0);
      bf16x8 wf0b = *(const bf16x8*)(wr + k0 + 32);
      bf16x8 wf1a = *(const bf16x8*)(wr + 16*DMODEL + k0);
      bf16x8 wf1b = *(const bf16x8*)(wr + 16*DMODEL + k0 + 32);
      bf16x8 af0a = *(const bf16x8*)(ar + k0);
      bf16x8 af0b = *(const bf16x8*)(ar + k0 + 32);
      bf16x8 af1a = *(const bf16x8*)(ar + 16*DMODEL + k0);
      bf16x8 af1b = *(const bf16x8*)(ar + 16*DMODEL + k0 + 32);
      acc[0][0] = __builtin_amdgcn_mfma_f32_16x16x32_bf16(af0a, wf0a, acc[0][0], 0,0,0);
      acc[0][0] = __builtin_amdgcn_mfma_f32_16x16x32_bf16(af0b, wf0b, acc[0][0], 0,0,0);
      acc[0][1] = __builtin_amdgcn_mfma_f32_16x16x32_bf16(af0a, wf1a, acc[0][1], 0,0,0);
      acc[0][1] = __builtin_amdgcn_mfma_f32_16x16x32_bf16(af0b, wf1b, acc[0][1], 0,0,0);
      acc[1][0] = __builtin_amdgcn_mfma_f32_16x16x32_bf16(af1a, wf0a, acc[1][0], 0,0,0);
      acc[1][0] = __builtin_amdgcn_mfma_f32_16x16x32_bf16(af1b, wf0b, acc[1][0], 0,0,0);
      acc[1][1] = __builtin_amdgcn_mfma_f32_16x16x32_bf16(af1a, wf1a, acc[1][1], 0,0,0);
      acc[1][1] = __builtin_amdgcn_mfma_f32_16x16x32_bf16(af1b, wf1b, acc[1][1], 0,0,0);
    }
    #pragma unroll
    for (int mf=0; mf<2; mf++){
      int m = m0 + mf*16 + g*4;
      #pragma unroll
      for (int nf=0; nf<2; nf++){
        int n = n0 + nf*16 + li;
        float bn = bias[n];
        u16x4 o;
        #pragma unroll
        for (int r=0; r<4; r++) o[r] = f2bf(acc[mf][nf][r] + bn);
        *(u16x4*)(Vt + (((size_t)(n>>6))<<16) + ((size_t)(n&63)<<10) + m) = o;
      }
    }
  }
}

// ================= MFMA attention; p = wg * exp(s/8); transposed partial store =================
__global__ __launch_bounds__(256) void k_attn2(const ushort_t* __restrict__ Qb,
     const ushort_t* __restrict__ Kb, const ushort_t* __restrict__ Vt,
     const _Float16* __restrict__ wg, ushort_t* __restrict__ Xpt, float* __restrict__ rsp){
  const int t = threadIdx.x;
  const int lane = t & 63;
  const int w = t >> 6;
  const int id = blockIdx.x*4 + w;
  const int it = id & 63;
  const int h  = (id >> 6) & 7;
  const int sp = id >> 9;
  const int i0 = it*16;
  const int li = lane & 15, g = lane >> 4;

  const ushort_t* qp = Qb + (size_t)(i0+li)*DMODEL + h*DKH + g*8;
  bf16x8 qf0 = *(const bf16x8*)(qp);
  bf16x8 qf1 = *(const bf16x8*)(qp + 32);

  f32x4 xacc[4];
  #pragma unroll
  for (int mf=0; mf<4; mf++) xacc[mf] = (f32x4){0.f,0.f,0.f,0.f};
  float rsum = 0.f;

  const ushort_t*  kbase = Kb + (size_t)li*DMODEL + h*DKH + g*8;
  const _Float16*  gbase = wg + ((size_t)h<<20) + ((size_t)(i0+li)<<10) + g*4;
  const ushort_t*  vbase = Vt + ((size_t)h<<16) + (size_t)li*NTOK + g*4;

  const int jbeg = sp*(NTOK/NSPLIT), jend = jbeg + NTOK/NSPLIT;
  for (int j0 = jbeg; j0 < jend; j0 += 32){
    const ushort_t* kp = kbase + (size_t)j0*DMODEL;
    bf16x8 a00 = *(const bf16x8*)(kp);
    bf16x8 a01 = *(const bf16x8*)(kp + 32);
    bf16x8 a10 = *(const bf16x8*)(kp + 16*DMODEL);
    bf16x8 a11 = *(const bf16x8*)(kp + 16*DMODEL + 32);
    f32x4 s0 = (f32x4){0.f,0.f,0.f,0.f};
    f32x4 s1 = (f32x4){0.f,0.f,0.f,0.f};
    s0 = __builtin_amdgcn_mfma_f32_16x16x32_bf16(a00, qf0, s0, 0,0,0);
    s0 = __builtin_amdgcn_mfma_f32_16x16x32_bf16(a01, qf1, s0, 0,0,0);
    s1 = __builtin_amdgcn_mfma_f32_16x16x32_bf16(a10, qf0, s1, 0,0,0);
    s1 = __builtin_amdgcn_mfma_f32_16x16x32_bf16(a11, qf1, s1, 0,0,0);
    f16x4 g0 = *(const f16x4*)(gbase + j0);
    f16x4 g1 = *(const f16x4*)(gbase + j0 + 16);
    float p[8];
    #pragma unroll
    for (int r=0; r<4; r++){ p[r]   = (float)g0[r] * __expf(s0[r]*0.125f); rsum += p[r]; }
    #pragma unroll
    for (int r=0; r<4; r++){ p[4+r] = (float)g1[r] * __expf(s1[r]*0.125f); rsum += p[4+r]; }
    bf16x8 pb;
    pb[0]=(__bf16)p[0]; pb[1]=(__bf16)p[1]; pb[2]=(__bf16)p[2]; pb[3]=(__bf16)p[3];
    pb[4]=(__bf16)p[4]; pb[5]=(__bf16)p[5]; pb[6]=(__bf16)p[6]; pb[7]=(__bf16)p[7];
    #pragma unroll
    for (int mf=0; mf<4; mf++){
      const ushort_t* vp = vbase + (size_t)mf*16*NTOK + j0;
      bf16x4 lo = *(const bf16x4*)(vp);
      bf16x4 hi = *(const bf16x4*)(vp + 16);
      bf16x8 vf = __builtin_shufflevector(lo, hi, 0,1,2,3,4,5,6,7);
      xacc[mf] = __builtin_amdgcn_mfma_f32_16x16x32_bf16(vf, pb, xacc[mf], 0,0,0);
    }
  }
  rsum += __shfl_xor(rsum, 16, 64);
  rsum += __shfl_xor(rsum, 32, 64);
  if (lane < 16) rsp[((size_t)sp*NHEAD + h)*NTOK + i0 + li] = rsum;
  // LDS transpose -> Xpt[sp][h][dk][i] (bf16) so the LN-side read is contiguous
  __shared__ float xt[4][16][68];
  #pragma unroll
  for (int mf=0; mf<4; mf++)
    *(f32x4*)&xt[w][li][mf*16 + g*4] = xacc[mf];
  __syncthreads();
  float xv[16];
  #pragma unroll
  for (int r=0; r<16; r++) xv[r] = xt[w][r][lane];
  u16x8 o0, o1;
  #pragma unroll
  for (int r=0; r<8; r++){ o0[r] = f2bf(xv[r]); o1[r] = f2bf(xv[8+r]); }
  ushort_t* xp = Xpt + (((size_t)sp*NHEAD + h)*DKH + lane)*NTOK + i0;
  *(u16x8*)(xp)     = o0;
  *(u16x8*)(xp + 8) = o1;
}

// ================= combine + scrambled-reshape LN (fused) =================
// attn[n][d] = X[h=n>>7][m=(n&1)*512+d][dk=(n>>1)&63], X = (sum_sp Xpt)/(sum_sp rsp)
__global__ __launch_bounds__(256) void k_ln0c(const ushort_t* __restrict__ Xpt,
        const float* __restrict__ rsp, const float* __restrict__ resid,
        const float* __restrict__ g, const float* __restrict__ b,
        float* __restrict__ out0, ushort_t* __restrict__ out0b){
  const int n = blockIdx.x, t = threadIdx.x;
  const int h = n >> 7, dk = (n >> 1) & 63, mo = (n & 1)*512;
  const int i0 = mo + t, i1 = mo + t + 256;
  float s0v=0.f, s1v=0.f, r0=0.f, r1=0.f;
  #pragma unroll
  for (int sp=0; sp<NSPLIT; sp++){
    const ushort_t* base = Xpt + (((size_t)sp*NHEAD + h)*DKH + dk)*NTOK;
    s0v += bf2f(base[i0]);
    s1v += bf2f(base[i1]);
    const float* rb = rsp + ((size_t)sp*NHEAD + h)*NTOK;
    r0 += rb[i0];
    r1 += rb[i1];
  }
  float x0 = s0v/r0 + resid[(size_t)n*DMODEL + t];
  float x1 = s1v/r1 + resid[(size_t)n*DMODEL + t + 256];
  __shared__ float red[8];
  float s = wave_sum_f(x0 + x1);
  float q = wave_sum_f(x0*x0 + x1*x1);
  int wid = t >> 6, lane = t & 63;
  if (lane == 0){ red[wid] = s; red[4+wid] = q; }
  __syncthreads();
  float S = red[0]+red[1]+red[2]+red[3];
  float Q = red[4]+red[5]+red[6]+red[7];
  float mean = S * (1.0f/512.0f);
  float var = Q * (1.0f/512.0f) - mean*mean;
  float rs = rsqrtf(var + 1e-5f);
  float y0 = (x0-mean)*rs*g[t] + b[t];
  float y1 = (x1-mean)*rs*g[t+256] + b[t+256];
  out0[(size_t)n*DMODEL + t]        = y0;
  out0[(size_t)n*DMODEL + t + 256]  = y1;
  out0b[(size_t)n*DMODEL + t]       = f2bf(y0);
  out0b[(size_t)n*DMODEL + t + 256] = f2bf(y1);
}

// ================= O-projection + residual + final LN (fused) =================
// block = 16 m-rows x full 512 n (8 waves, each 16x64); LN stats via shfl + LDS cross-wave reduce.
__global__ __launch_bounds__(512) void k_mm_o_ln(
    const ushort_t* __restrict__ A, const ushort_t* __restrict__ W,
    const float* __restrict__ bo, const float* __restrict__ add,
    const float* __restrict__ lng, const float* __restrict__ lnb, float* __restrict__ out){
  const int t = threadIdx.x, lane = t & 63, w = t >> 6;
  const int li = lane & 15, g = lane >> 4;
  const int m0 = blockIdx.x*16;
  const int n0 = w*64;
  const ushort_t* ar = A + (size_t)(m0+li)*DMODEL + g*8;
  const ushort_t* wr = W + (size_t)(n0+li)*DMODEL + g*8;
  f32x4 acc[4] = {};
  #pragma unroll
  for (int k0=0; k0<DMODEL; k0+=64){
    bf16x8 afa = *(const bf16x8*)(ar + k0);
    bf16x8 afb = *(const bf16x8*)(ar + k0 + 32);
    #pragma unroll
    for (int nf=0; nf<4; nf++){
      const ushort_t* wp = wr + (size_t)nf*16*DMODEL + k0;
      bf16x8 wfa = *(const bf16x8*)(wp);
      bf16x8 wfb = *(const bf16x8*)(wp + 32);
      acc[nf] = __builtin_amdgcn_mfma_f32_16x16x32_bf16(wfa, afa, acc[nf], 0,0,0);
      acc[nf] = __builtin_amdgcn_mfma_f32_16x16x32_bf16(wfb, afb, acc[nf], 0,0,0);
    }
  }
  const int m = m0 + li;
  float s = 0.f, qq = 0.f;
  f32x4 v[4];
  #pragma unroll
  for (int nf=0; nf<4; nf++){
    int n = n0 + nf*16 + g*4;
    f32x4 b4 = *(const f32x4*)(bo + n);
    f32x4 a4 = *(const f32x4*)(add + (size_t)m*DMODEL + n);
    #pragma unroll
    for (int r=0; r<4; r++){
      float x = acc[nf][r] + b4[r] + a4[r];
      v[nf][r] = x; s += x; qq += x*x;
    }
  }
  s  += __shfl_xor(s, 16, 64);  s  += __shfl_xor(s, 32, 64);
  qq += __shfl_xor(qq, 16, 64); qq += __shfl_xor(qq, 32, 64);
  __shared__ float red[8][16][2];
  if (g == 0){ red[w][li][0] = s; red[w][li][1] = qq; }
  __syncthreads();
  float S = 0.f, Q = 0.f;
  #pragma unroll
  for (int u=0; u<8; u++){ S += red[u][li][0]; Q += red[u][li][1]; }
  float mean = S * (1.0f/512.0f);
  float var = Q * (1.0f/512.0f) - mean*mean;
  float rs = rsqrtf(var + 1e-5f);
  #pragma unroll
  for (int nf=0; nf<4; nf++){
    int n = n0 + nf*16 + g*4;
    f32x4 g4 = *(const f32x4*)(lng + n);
    f32x4 be = *(const f32x4*)(lnb + n);
    f32x4 o;
    #pragma unroll
    for (int r=0; r<4; r++) o[r] = (v[nf][r]-mean)*rs*g4[r] + be[r];
    *(f32x4*)(out + (size_t)m*DMODEL + n) = o;
  }
}

extern "C" void kernel_launch(void* const* d_in, const int* in_sizes, int n_in,
                              void* d_out, int out_size, void* d_ws, size_t ws_size,
                              hipStream_t stream){
  (void)in_sizes; (void)n_in; (void)out_size; (void)ws_size;
  const float* in_q = (const float*)d_in[0];
  const float* in_k = (const float*)d_in[1];
  const float* in_v = (const float*)d_in[2];
  const float* box  = (const float*)d_in[3];
  const float* Wq   = (const float*)d_in[4];
  const float* bq   = (const float*)d_in[5];
  const float* Wk   = (const float*)d_in[6];
  const float* bk   = (const float*)d_in[7];
  const float* Wv   = (const float*)d_in[8];
  const float* bv   = (const float*)d_in[9];
  const float* Wo   = (const float*)d_in[10];
  const float* bo   = (const float*)d_in[11];
  const float* WGw  = (const float*)d_in[12];
  const float* WGb  = (const float*)d_in[13];
  const float* ln0g = (const float*)d_in[14];
  const float* ln0b = (const float*)d_in[15];
  const float* lng  = (const float*)d_in[16];
  const float* lnb  = (const float*)d_in[17];

  float* ws = (float*)d_ws;
  // ---- ws layout (float-offset units), total 36.8 MB ----
  ushort_t* Abq  = (ushort_t*)(ws + 0);             // [1024][512] bf16
  ushort_t* Abk  = (ushort_t*)(ws + 262144);
  ushort_t* Abv  = (ushort_t*)(ws + 524288);
  ushort_t* Wqb  = (ushort_t*)(ws + 786432);        // [512][512] bf16
  ushort_t* Wkb  = (ushort_t*)(ws + 917504);
  ushort_t* Wvb  = (ushort_t*)(ws + 1048576);
  ushort_t* Wob  = (ushort_t*)(ws + 1179648);
  ushort_t* Qb   = (ushort_t*)(ws + 1310720);       // [1024][512] bf16
  ushort_t* Kb   = (ushort_t*)(ws + 1572864);
  ushort_t* Vt   = (ushort_t*)(ws + 1835008);       // [8][64][1024] bf16
  _Float16* wg16 = (_Float16*)(ws + 2097152);       // [8][1024][1024] fp16 (16 MB)
  ushort_t* Xpt  = (ushort_t*)(ws + 6291456);       // [4][8][64][1024] bf16 (8 MB)
  float*    rsp  = ws + 8388608;                    // [4][8][1024]
  float*    out0 = ws + 8421376;                    // [1024][512] f32
  ushort_t* out0b= (ushort_t*)(ws + 8945664);       // [1024][512] bf16
  float*    out  = (float*)d_out;

  k_pre<<<dim3(2304), dim3(256), 0, stream>>>(box, WGw, WGb, wg16,
            in_q, in_k, in_v, Wq, Wk, Wv, Wo,
            Abq, Abk, Abv, Wqb, Wkb, Wvb, Wob);
  k_mm_qkv<<<dim3(8,32,3), dim3(128), 0, stream>>>(Abq, Abk, Abv, Wqb, Wkb, Wvb,
            bq, bk, bv, Qb, Kb, Vt);
  k_attn2<<<dim3(512), dim3(256), 0, stream>>>(Qb, Kb, Vt, wg16, Xpt, rsp);
  k_ln0c<<<dim3(1024), dim3(256), 0, stream>>>(Xpt, rsp, in_q, ln0g, ln0b, out0, out0b);
  k_mm_o_ln<<<dim3(64), dim3(512), 0, stream>>>(out0b, Wob, bo, out0, lng, lnb, out);
}

// Round 5
// 90.182 us; speedup vs baseline: 2.1624x; 1.0068x over previous
//
#include <hip/hip_runtime.h>
#include <cstddef>

#define NTOK 1024
#define DMODEL 512
#define NHEAD 8
#define DKH 64
#define NSPLIT 4

typedef __attribute__((ext_vector_type(4))) float f32x4;
typedef __attribute__((ext_vector_type(8))) __bf16 bf16x8;
typedef __attribute__((ext_vector_type(4))) __bf16 bf16x4;
typedef __attribute__((ext_vector_type(4))) unsigned short u16x4;
typedef __attribute__((ext_vector_type(8))) unsigned short u16x8;
typedef __attribute__((ext_vector_type(4))) _Float16 f16x4;
typedef unsigned short ushort_t;

__device__ __forceinline__ float wave_sum_f(float v){
  #pragma unroll
  for (int m=1; m<64; m<<=1) v += __shfl_xor(v, m, 64);
  return v;
}
__device__ __forceinline__ unsigned short f2bf(float f){
  __bf16 b = (__bf16)f;
  return __builtin_bit_cast(unsigned short, b);
}
__device__ __forceinline__ float bf2f(unsigned short u){
  return (float)__builtin_bit_cast(__bf16, u);
}

// ---- native transcendental ops (avoid OCML library routines) ----
// v_sin/v_cos take input in REVOLUTIONS; v_fract does the range reduction.
__device__ __forceinline__ float fract_hw(float x){
  float r; asm("v_fract_f32 %0, %1" : "=v"(r) : "v"(x)); return r;
}
__device__ __forceinline__ float sin_rev(float rev){
  float f = fract_hw(rev);
  float s; asm("v_sin_f32 %0, %1" : "=v"(s) : "v"(f)); return s;
}
__device__ __forceinline__ float cos_rev(float rev){
  float f = fract_hw(rev);
  float c; asm("v_cos_f32 %0, %1" : "=v"(c) : "v"(f)); return c;
}
__device__ __forceinline__ float log_hw(float x){          // ln(x)
  float l; asm("v_log_f32 %0, %1" : "=v"(l) : "v"(x));
  return 0.69314718056f * l;
}
__device__ __forceinline__ float exp_hw(float x){          // e^x
  float y = x * 1.44269504f;
  float e; asm("v_exp_f32 %0, %1" : "=v"(e) : "v"(y));
  return e;
}

// ================= k_pre: fused [gate-MFMA (blocks 0..1023)] + [fp32->bf16 cvt (blocks 1024..2303)] ====
// Gate: wg16[h][i][j] = max(relu(emb(i,j).WGw[h] + WGb[h]), 6.1e-5) in fp16 (log-free softmax identity).
// Trig via native v_sin/v_cos in REVOLUTIONS: DMrev = 100*1000^(-e/8) / (2*pi).
__global__ __launch_bounds__(256) void k_pre(
    const float* __restrict__ box, const float* __restrict__ WGw, const float* __restrict__ WGb,
    _Float16* __restrict__ wg16,
    const float* __restrict__ q, const float* __restrict__ k, const float* __restrict__ v,
    const float* __restrict__ wq, const float* __restrict__ wk, const float* __restrict__ wv,
    const float* __restrict__ wo,
    ushort_t* __restrict__ qb, ushort_t* __restrict__ kb, ushort_t* __restrict__ vb,
    ushort_t* __restrict__ wqb, ushort_t* __restrict__ wkb, ushort_t* __restrict__ wvb,
    ushort_t* __restrict__ wob){
  const int t = threadIdx.x;
  if (blockIdx.x >= 1024){
    // ---- cvt blocks ----
    int gi = (blockIdx.x - 1024)*256 + t;   // 8-elem group index, 327680 total
    const float* s; ushort_t* d; int off;
    if (gi < 196608){
      int seg = gi >> 16;
      off = (gi & 65535)*8;
      s = seg==0 ? q : seg==1 ? k : v;
      d = seg==0 ? qb : seg==1 ? kb : vb;
    } else {
      int g2 = gi - 196608;
      int seg = g2 >> 15;
      off = (g2 & 32767)*8;
      s = seg==0 ? wq : seg==1 ? wk : seg==2 ? wv : wo;
      d = seg==0 ? wqb : seg==1 ? wkb : seg==2 ? wvb : wob;
    }
    float4 a = *(const float4*)(s + off);
    float4 b = *(const float4*)(s + off + 4);
    u16x4 o0, o1;
    o0[0]=f2bf(a.x); o0[1]=f2bf(a.y); o0[2]=f2bf(a.z); o0[3]=f2bf(a.w);
    o1[0]=f2bf(b.x); o1[1]=f2bf(b.y); o1[2]=f2bf(b.z); o1[3]=f2bf(b.w);
    *(u16x4*)(d + off) = o0;
    *(u16x4*)(d + off + 4) = o1;
    return;
  }
  // ---- gate blocks: one i per block, 4 waves x 256-j quarters ----
  __shared__ float arr[4][1024];   // cx, cy, lw, lh
  #pragma unroll
  for (int u=0; u<4; u++){
    int idx = u*256 + t;
    float4 b4 = *(const float4*)(box + idx*4);
    arr[0][idx] = (b4.x + b4.z)*0.5f;
    arr[1][idx] = (b4.y + b4.w)*0.5f;
    arr[2][idx] = log_hw(b4.z - b4.x + 1.0f);
    arr[3][idx] = log_hw(b4.w - b4.y + 1.0f);
  }
  const int i = blockIdx.x;
  const int lane = t & 63, w = t >> 6, li = lane & 15, g = lane >> 4;
  float4 bi = *(const float4*)(box + i*4);
  float wi = bi.z - bi.x + 1.0f, hi = bi.w - bi.y + 1.0f;
  float Pi = (g==0) ? (bi.x+bi.z)*0.5f : (g==1) ? (bi.y+bi.w)*0.5f
           : (g==2) ? log_hw(wi) : log_hw(hi);
  float Ri = (g==0) ? 1.0f/wi : (g==1) ? 1.0f/hi : 1.0f;
  const bool doLog = (g < 2);
  // B-frags: WGw sin-half and cos-half (cols = heads, zero for li>=8)
  bf16x8 wfs = {}, wfc = {};
  float wgb_li = 0.0f;
  if (li < 8){
    #pragma unroll
    for (int e=0; e<8; e++){
      wfs[e] = (__bf16)WGw[li*64 + g*8 + e];
      wfc[e] = (__bf16)WGw[li*64 + 32 + g*8 + e];
    }
    wgb_li = WGb[li];
  }
  __syncthreads();
  const float* parr = &arr[g][0];
  // DM[e]/(2*pi): angles in revolutions for v_sin/v_cos
  const float DMrev[8] = {15.9154943f, 6.7115094f, 2.8302196f, 1.1934938f,
                          0.5032921f, 0.2122365f, 0.08949941f, 0.0377416f};
  const int jbeg = w*256;
  for (int it=0; it<16; ++it){
    int j = jbeg + it*16 + li;
    float diff = (Pi - parr[j])*Ri;
    float lg = log_hw(fmaxf(fabsf(diff), 1e-3f));
    float dv = doLog ? lg : diff;
    bf16x8 afs, afc;
    #pragma unroll
    for (int e=0; e<8; e++){
      float rev = dv * DMrev[e];
      afs[e] = (__bf16)sin_rev(rev);
      afc[e] = (__bf16)cos_rev(rev);
    }
    f32x4 acc = (f32x4){0.f,0.f,0.f,0.f};
    acc = __builtin_amdgcn_mfma_f32_16x16x32_bf16(afs, wfs, acc, 0,0,0);
    acc = __builtin_amdgcn_mfma_f32_16x16x32_bf16(afc, wfc, acc, 0,0,0);
    if (li < 8){
      // lane holds out[j = jbeg+it*16+g*4+r][h = li]
      f16x4 o;
      #pragma unroll
      for (int r=0; r<4; r++)
        o[r] = (_Float16)fmaxf(acc[r] + wgb_li, 6.103515625e-05f);
      *(f16x4*)(wg16 + (((size_t)li<<20) + ((size_t)i<<10) + jbeg + it*16 + g*4)) = o;
    }
  }
}

// ================= MFMA QKV projection (unchanged structure) =================
__global__ __launch_bounds__(128) void k_mm_qkv(
    const ushort_t* __restrict__ Aq, const ushort_t* __restrict__ Ak, const ushort_t* __restrict__ Av,
    const ushort_t* __restrict__ Wqb, const ushort_t* __restrict__ Wkb, const ushort_t* __restrict__ Wvb,
    const float* __restrict__ bq, const float* __restrict__ bk, const float* __restrict__ bv,
    ushort_t* __restrict__ Qb, ushort_t* __restrict__ Kb, ushort_t* __restrict__ Vt){
  const int z = blockIdx.z;
  const ushort_t* A = z==0 ? Aq : z==1 ? Ak : Av;
  const ushort_t* W = z==0 ? Wqb : z==1 ? Wkb : Wvb;
  const float* bias = z==0 ? bq : z==1 ? bk : bv;
  const int t = threadIdx.x, lane = t & 63, w = t >> 6;
  const int li = lane & 15, g = lane >> 4;
  const int m0 = blockIdx.y*32;
  const int n0 = blockIdx.x*64 + w*32;
  const ushort_t* ar = A + (size_t)(m0+li)*DMODEL + g*8;
  const ushort_t* wr = W + (size_t)(n0+li)*DMODEL + g*8;
  f32x4 acc[2][2] = {};
  if (z < 2){
    #pragma unroll
    for (int k0=0; k0<DMODEL; k0+=64){
      bf16x8 wf0a = *(const bf16x8*)(wr + k0);
      bf16x8 wf0b = *(const bf16x8*)(wr + k0 + 32);
      bf16x8 wf1a = *(const bf16x8*)(wr + 16*DMODEL + k0);
      bf16x8 wf1b = *(const bf16x8*)(wr + 16*DMODEL + k0 + 32);
      bf16x8 af0a = *(const bf16x8*)(ar + k0);
      bf16x8 af0b = *(const bf16x8*)(ar + k0 + 32);
      bf16x8 af1a = *(const bf16x8*)(ar + 16*DMODEL + k0);
      bf16x8 af1b = *(const bf16x8*)(ar + 16*DMODEL + k0 + 32);
      acc[0][0] = __builtin_amdgcn_mfma_f32_16x16x32_bf16(wf0a, af0a, acc[0][0], 0,0,0);
      acc[0][0] = __builtin_amdgcn_mfma_f32_16x16x32_bf16(wf0b, af0b, acc[0][0], 0,0,0);
      acc[0][1] = __builtin_amdgcn_mfma_f32_16x16x32_bf16(wf0a, af1a, acc[0][1], 0,0,0);
      acc[0][1] = __builtin_amdgcn_mfma_f32_16x16x32_bf16(wf0b, af1b, acc[0][1], 0,0,0);
      acc[1][0] = __builtin_amdgcn_mfma_f32_16x16x32_bf16(wf1a, af0a, acc[1][0], 0,0,0);
      acc[1][0] = __builtin_amdgcn_mfma_f32_16x16x32_bf16(wf1b, af0b, acc[1][0], 0,0,0);
      acc[1][1] = __builtin_amdgcn_mfma_f32_16x16x32_bf16(wf1a, af1a, acc[1][1], 0,0,0);
      acc[1][1] = __builtin_amdgcn_mfma_f32_16x16x32_bf16(wf1b, af1b, acc[1][1], 0,0,0);
    }
    ushort_t* C = z ? Kb : Qb;
    #pragma unroll
    for (int nf=0; nf<2; nf++){
      int n = n0 + nf*16 + g*4;
      float4 b4 = *(const float4*)(bias + n);
      const float* bp = (const float*)&b4;
      #pragma unroll
      for (int mf=0; mf<2; mf++){
        int m = m0 + mf*16 + li;
        u16x4 o;
        #pragma unroll
        for (int r=0; r<4; r++) o[r] = f2bf(acc[nf][mf][r] + bp[r]);
        *(u16x4*)(C + (size_t)m*DMODEL + n) = o;
      }
    }
  } else {
    #pragma unroll
    for (int k0=0; k0<DMODEL; k0+=64){
      bf16x8 wf0a = *(const bf16x8*)(wr + k0);
      bf16x8 wf0b = *(const bf16x8*)(wr + k0 + 32);
      bf16x8 wf1a = *(const bf16x8*)(wr + 16*DMODEL + k0);
      bf16x8 wf1b = *(const bf16x8*)(wr + 16*DMODEL + k0 + 32);
      bf16x8 af0a = *(const bf16x8*)(ar + k0);
      bf16x8 af0b = *(const bf16x8*)(ar + k0 + 32);
      bf16x8 af1a = *(const bf16x8*)(ar + 16*DMODEL + k0);
      bf16x8 af1b = *(const bf16x8*)(ar + 16*DMODEL + k0 + 32);
      acc[0][0] = __builtin_amdgcn_mfma_f32_16x16x32_bf16(af0a, wf0a, acc[0][0], 0,0,0);
      acc[0][0] = __builtin_amdgcn_mfma_f32_16x16x32_bf16(af0b, wf0b, acc[0][0], 0,0,0);
      acc[0][1] = __builtin_amdgcn_mfma_f32_16x16x32_bf16(af0a, wf1a, acc[0][1], 0,0,0);
      acc[0][1] = __builtin_amdgcn_mfma_f32_16x16x32_bf16(af0b, wf1b, acc[0][1], 0,0,0);
      acc[1][0] = __builtin_amdgcn_mfma_f32_16x16x32_bf16(af1a, wf0a, acc[1][0], 0,0,0);
      acc[1][0] = __builtin_amdgcn_mfma_f32_16x16x32_bf16(af1b, wf0b, acc[1][0], 0,0,0);
      acc[1][1] = __builtin_amdgcn_mfma_f32_16x16x32_bf16(af1a, wf1a, acc[1][1], 0,0,0);
      acc[1][1] = __builtin_amdgcn_mfma_f32_16x16x32_bf16(af1b, wf1b, acc[1][1], 0,0,0);
    }
    #pragma unroll
    for (int mf=0; mf<2; mf++){
      int m = m0 + mf*16 + g*4;
      #pragma unroll
      for (int nf=0; nf<2; nf++){
        int n = n0 + nf*16 + li;
        float bn = bias[n];
        u16x4 o;
        #pragma unroll
        for (int r=0; r<4; r++) o[r] = f2bf(acc[mf][nf][r] + bn);
        *(u16x4*)(Vt + (((size_t)(n>>6))<<16) + ((size_t)(n&63)<<10) + m) = o;
      }
    }
  }
}

// ================= MFMA attention; p = wg * exp(s/8); transposed partial store =================
__global__ __launch_bounds__(256) void k_attn2(const ushort_t* __restrict__ Qb,
     const ushort_t* __restrict__ Kb, const ushort_t* __restrict__ Vt,
     const _Float16* __restrict__ wg, ushort_t* __restrict__ Xpt, float* __restrict__ rsp){
  const int t = threadIdx.x;
  const int lane = t & 63;
  const int w = t >> 6;
  const int id = blockIdx.x*4 + w;
  const int it = id & 63;
  const int h  = (id >> 6) & 7;
  const int sp = id >> 9;
  const int i0 = it*16;
  const int li = lane & 15, g = lane >> 4;

  const ushort_t* qp = Qb + (size_t)(i0+li)*DMODEL + h*DKH + g*8;
  bf16x8 qf0 = *(const bf16x8*)(qp);
  bf16x8 qf1 = *(const bf16x8*)(qp + 32);

  f32x4 xacc[4];
  #pragma unroll
  for (int mf=0; mf<4; mf++) xacc[mf] = (f32x4){0.f,0.f,0.f,0.f};
  float rsum = 0.f;

  const ushort_t*  kbase = Kb + (size_t)li*DMODEL + h*DKH + g*8;
  const _Float16*  gbase = wg + ((size_t)h<<20) + ((size_t)(i0+li)<<10) + g*4;
  const ushort_t*  vbase = Vt + ((size_t)h<<16) + (size_t)li*NTOK + g*4;

  const int jbeg = sp*(NTOK/NSPLIT), jend = jbeg + NTOK/NSPLIT;
  for (int j0 = jbeg; j0 < jend; j0 += 32){
    const ushort_t* kp = kbase + (size_t)j0*DMODEL;
    bf16x8 a00 = *(const bf16x8*)(kp);
    bf16x8 a01 = *(const bf16x8*)(kp + 32);
    bf16x8 a10 = *(const bf16x8*)(kp + 16*DMODEL);
    bf16x8 a11 = *(const bf16x8*)(kp + 16*DMODEL + 32);
    f32x4 s0 = (f32x4){0.f,0.f,0.f,0.f};
    f32x4 s1 = (f32x4){0.f,0.f,0.f,0.f};
    s0 = __builtin_amdgcn_mfma_f32_16x16x32_bf16(a00, qf0, s0, 0,0,0);
    s0 = __builtin_amdgcn_mfma_f32_16x16x32_bf16(a01, qf1, s0, 0,0,0);
    s1 = __builtin_amdgcn_mfma_f32_16x16x32_bf16(a10, qf0, s1, 0,0,0);
    s1 = __builtin_amdgcn_mfma_f32_16x16x32_bf16(a11, qf1, s1, 0,0,0);
    f16x4 g0 = *(const f16x4*)(gbase + j0);
    f16x4 g1 = *(const f16x4*)(gbase + j0 + 16);
    float p[8];
    #pragma unroll
    for (int r=0; r<4; r++){ p[r]   = (float)g0[r] * exp_hw(s0[r]*0.125f); rsum += p[r]; }
    #pragma unroll
    for (int r=0; r<4; r++){ p[4+r] = (float)g1[r] * exp_hw(s1[r]*0.125f); rsum += p[4+r]; }
    bf16x8 pb;
    pb[0]=(__bf16)p[0]; pb[1]=(__bf16)p[1]; pb[2]=(__bf16)p[2]; pb[3]=(__bf16)p[3];
    pb[4]=(__bf16)p[4]; pb[5]=(__bf16)p[5]; pb[6]=(__bf16)p[6]; pb[7]=(__bf16)p[7];
    #pragma unroll
    for (int mf=0; mf<4; mf++){
      const ushort_t* vp = vbase + (size_t)mf*16*NTOK + j0;
      bf16x4 lo = *(const bf16x4*)(vp);
      bf16x4 hi = *(const bf16x4*)(vp + 16);
      bf16x8 vf = __builtin_shufflevector(lo, hi, 0,1,2,3,4,5,6,7);
      xacc[mf] = __builtin_amdgcn_mfma_f32_16x16x32_bf16(vf, pb, xacc[mf], 0,0,0);
    }
  }
  rsum += __shfl_xor(rsum, 16, 64);
  rsum += __shfl_xor(rsum, 32, 64);
  if (lane < 16) rsp[((size_t)sp*NHEAD + h)*NTOK + i0 + li] = rsum;
  // LDS transpose -> Xpt[sp][h][dk][i] (bf16) so the LN-side read is contiguous
  __shared__ float xt[4][16][68];
  #pragma unroll
  for (int mf=0; mf<4; mf++)
    *(f32x4*)&xt[w][li][mf*16 + g*4] = xacc[mf];
  __syncthreads();
  float xv[16];
  #pragma unroll
  for (int r=0; r<16; r++) xv[r] = xt[w][r][lane];
  u16x8 o0, o1;
  #pragma unroll
  for (int r=0; r<8; r++){ o0[r] = f2bf(xv[r]); o1[r] = f2bf(xv[8+r]); }
  ushort_t* xp = Xpt + (((size_t)sp*NHEAD + h)*DKH + lane)*NTOK + i0;
  *(u16x8*)(xp)     = o0;
  *(u16x8*)(xp + 8) = o1;
}

// ================= combine + scrambled-reshape LN (fused) =================
__global__ __launch_bounds__(256) void k_ln0c(const ushort_t* __restrict__ Xpt,
        const float* __restrict__ rsp, const float* __restrict__ resid,
        const float* __restrict__ g, const float* __restrict__ b,
        float* __restrict__ out0, ushort_t* __restrict__ out0b){
  const int n = blockIdx.x, t = threadIdx.x;
  const int h = n >> 7, dk = (n >> 1) & 63, mo = (n & 1)*512;
  const int i0 = mo + t, i1 = mo + t + 256;
  float s0v=0.f, s1v=0.f, r0=0.f, r1=0.f;
  #pragma unroll
  for (int sp=0; sp<NSPLIT; sp++){
    const ushort_t* base = Xpt + (((size_t)sp*NHEAD + h)*DKH + dk)*NTOK;
    s0v += bf2f(base[i0]);
    s1v += bf2f(base[i1]);
    const float* rb = rsp + ((size_t)sp*NHEAD + h)*NTOK;
    r0 += rb[i0];
    r1 += rb[i1];
  }
  float x0 = s0v/r0 + resid[(size_t)n*DMODEL + t];
  float x1 = s1v/r1 + resid[(size_t)n*DMODEL + t + 256];
  __shared__ float red[8];
  float s = wave_sum_f(x0 + x1);
  float q = wave_sum_f(x0*x0 + x1*x1);
  int wid = t >> 6, lane = t & 63;
  if (lane == 0){ red[wid] = s; red[4+wid] = q; }
  __syncthreads();
  float S = red[0]+red[1]+red[2]+red[3];
  float Q = red[4]+red[5]+red[6]+red[7];
  float mean = S * (1.0f/512.0f);
  float var = Q * (1.0f/512.0f) - mean*mean;
  float rs = rsqrtf(var + 1e-5f);
  float y0 = (x0-mean)*rs*g[t] + b[t];
  float y1 = (x1-mean)*rs*g[t+256] + b[t+256];
  out0[(size_t)n*DMODEL + t]        = y0;
  out0[(size_t)n*DMODEL + t + 256]  = y1;
  out0b[(size_t)n*DMODEL + t]       = f2bf(y0);
  out0b[(size_t)n*DMODEL + t + 256] = f2bf(y1);
}

// ================= O-projection + residual + final LN (fused) =================
__global__ __launch_bounds__(512) void k_mm_o_ln(
    const ushort_t* __restrict__ A, const ushort_t* __restrict__ W,
    const float* __restrict__ bo, const float* __restrict__ add,
    const float* __restrict__ lng, const float* __restrict__ lnb, float* __restrict__ out){
  const int t = threadIdx.x, lane = t & 63, w = t >> 6;
  const int li = lane & 15, g = lane >> 4;
  const int m0 = blockIdx.x*16;
  const int n0 = w*64;
  const ushort_t* ar = A + (size_t)(m0+li)*DMODEL + g*8;
  const ushort_t* wr = W + (size_t)(n0+li)*DMODEL + g*8;
  f32x4 acc[4] = {};
  #pragma unroll
  for (int k0=0; k0<DMODEL; k0+=64){
    bf16x8 afa = *(const bf16x8*)(ar + k0);
    bf16x8 afb = *(const bf16x8*)(ar + k0 + 32);
    #pragma unroll
    for (int nf=0; nf<4; nf++){
      const ushort_t* wp = wr + (size_t)nf*16*DMODEL + k0;
      bf16x8 wfa = *(const bf16x8*)(wp);
      bf16x8 wfb = *(const bf16x8*)(wp + 32);
      acc[nf] = __builtin_amdgcn_mfma_f32_16x16x32_bf16(wfa, afa, acc[nf], 0,0,0);
      acc[nf] = __builtin_amdgcn_mfma_f32_16x16x32_bf16(wfb, afb, acc[nf], 0,0,0);
    }
  }
  const int m = m0 + li;
  float s = 0.f, qq = 0.f;
  f32x4 v[4];
  #pragma unroll
  for (int nf=0; nf<4; nf++){
    int n = n0 + nf*16 + g*4;
    f32x4 b4 = *(const f32x4*)(bo + n);
    f32x4 a4 = *(const f32x4*)(add + (size_t)m*DMODEL + n);
    #pragma unroll
    for (int r=0; r<4; r++){
      float x = acc[nf][r] + b4[r] + a4[r];
      v[nf][r] = x; s += x; qq += x*x;
    }
  }
  s  += __shfl_xor(s, 16, 64);  s  += __shfl_xor(s, 32, 64);
  qq += __shfl_xor(qq, 16, 64); qq += __shfl_xor(qq, 32, 64);
  __shared__ float red[8][16][2];
  if (g == 0){ red[w][li][0] = s; red[w][li][1] = qq; }
  __syncthreads();
  float S = 0.f, Q = 0.f;
  #pragma unroll
  for (int u=0; u<8; u++){ S += red[u][li][0]; Q += red[u][li][1]; }
  float mean = S * (1.0f/512.0f);
  float var = Q * (1.0f/512.0f) - mean*mean;
  float rs = rsqrtf(var + 1e-5f);
  #pragma unroll
  for (int nf=0; nf<4; nf++){
    int n = n0 + nf*16 + g*4;
    f32x4 g4 = *(const f32x4*)(lng + n);
    f32x4 be = *(const f32x4*)(lnb + n);
    f32x4 o;
    #pragma unroll
    for (int r=0; r<4; r++) o[r] = (v[nf][r]-mean)*rs*g4[r] + be[r];
    *(f32x4*)(out + (size_t)m*DMODEL + n) = o;
  }
}

extern "C" void kernel_launch(void* const* d_in, const int* in_sizes, int n_in,
                              void* d_out, int out_size, void* d_ws, size_t ws_size,
                              hipStream_t stream){
  (void)in_sizes; (void)n_in; (void)out_size; (void)ws_size;
  const float* in_q = (const float*)d_in[0];
  const float* in_k = (const float*)d_in[1];
  const float* in_v = (const float*)d_in[2];
  const float* box  = (const float*)d_in[3];
  const float* Wq   = (const float*)d_in[4];
  const float* bq   = (const float*)d_in[5];
  const float* Wk   = (const float*)d_in[6];
  const float* bk   = (const float*)d_in[7];
  const float* Wv   = (const float*)d_in[8];
  const float* bv   = (const float*)d_in[9];
  const float* Wo   = (const float*)d_in[10];
  const float* bo   = (const float*)d_in[11];
  const float* WGw  = (const float*)d_in[12];
  const float* WGb  = (const float*)d_in[13];
  const float* ln0g = (const float*)d_in[14];
  const float* ln0b = (const float*)d_in[15];
  const float* lng  = (const float*)d_in[16];
  const float* lnb  = (const float*)d_in[17];

  float* ws = (float*)d_ws;
  // ---- ws layout (float-offset units), total 36.8 MB ----
  ushort_t* Abq  = (ushort_t*)(ws + 0);             // [1024][512] bf16
  ushort_t* Abk  = (ushort_t*)(ws + 262144);
  ushort_t* Abv  = (ushort_t*)(ws + 524288);
  ushort_t* Wqb  = (ushort_t*)(ws + 786432);        // [512][512] bf16
  ushort_t* Wkb  = (ushort_t*)(ws + 917504);
  ushort_t* Wvb  = (ushort_t*)(ws + 1048576);
  ushort_t* Wob  = (ushort_t*)(ws + 1179648);
  ushort_t* Qb   = (ushort_t*)(ws + 1310720);       // [1024][512] bf16
  ushort_t* Kb   = (ushort_t*)(ws + 1572864);
  ushort_t* Vt   = (ushort_t*)(ws + 1835008);       // [8][64][1024] bf16
  _Float16* wg16 = (_Float16*)(ws + 2097152);       // [8][1024][1024] fp16 (16 MB)
  ushort_t* Xpt  = (ushort_t*)(ws + 6291456);       // [4][8][64][1024] bf16 (8 MB)
  float*    rsp  = ws + 8388608;                    // [4][8][1024]
  float*    out0 = ws + 8421376;                    // [1024][512] f32
  ushort_t* out0b= (ushort_t*)(ws + 8945664);       // [1024][512] bf16
  float*    out  = (float*)d_out;

  k_pre<<<dim3(2304), dim3(256), 0, stream>>>(box, WGw, WGb, wg16,
            in_q, in_k, in_v, Wq, Wk, Wv, Wo,
            Abq, Abk, Abv, Wqb, Wkb, Wvb, Wob);
  k_mm_qkv<<<dim3(8,32,3), dim3(128), 0, stream>>>(Abq, Abk, Abv, Wqb, Wkb, Wvb,
            bq, bk, bv, Qb, Kb, Vt);
  k_attn2<<<dim3(512), dim3(256), 0, stream>>>(Qb, Kb, Vt, wg16, Xpt, rsp);
  k_ln0c<<<dim3(1024), dim3(256), 0, stream>>>(Xpt, rsp, in_q, ln0g, ln0b, out0, out0b);
  k_mm_o_ln<<<dim3(64), dim3(512), 0, stream>>>(out0b, Wob, bo, out0, lng, lnb, out);
}

// Round 6
// 77.918 us; speedup vs baseline: 2.5028x; 1.1574x over previous
//
#include <hip/hip_runtime.h>
#include <cstddef>

#define NTOK 1024
#define DMODEL 512
#define NHEAD 8
#define DKH 64
#define NSPLIT 4
#define JQ 256

typedef __attribute__((ext_vector_type(4))) float f32x4;
typedef __attribute__((ext_vector_type(8))) __bf16 bf16x8;
typedef __attribute__((ext_vector_type(4))) __bf16 bf16x4;
typedef __attribute__((ext_vector_type(4))) unsigned short u16x4;
typedef __attribute__((ext_vector_type(8))) unsigned short u16x8;
typedef __attribute__((ext_vector_type(4))) _Float16 f16x4;
typedef unsigned short ushort_t;

__device__ __forceinline__ float wave_sum_f(float v){
  #pragma unroll
  for (int m=1; m<64; m<<=1) v += __shfl_xor(v, m, 64);
  return v;
}
__device__ __forceinline__ unsigned short f2bf(float f){
  __bf16 b = (__bf16)f;
  return __builtin_bit_cast(unsigned short, b);
}
__device__ __forceinline__ float bf2f(unsigned short u){
  return (float)__builtin_bit_cast(__bf16, u);
}

// ---- native transcendental ops ----
__device__ __forceinline__ float fract_hw(float x){
  float r; asm("v_fract_f32 %0, %1" : "=v"(r) : "v"(x)); return r;
}
__device__ __forceinline__ float sin_rev(float rev){
  float f = fract_hw(rev);
  float s; asm("v_sin_f32 %0, %1" : "=v"(s) : "v"(f)); return s;
}
__device__ __forceinline__ float cos_rev(float rev){
  float f = fract_hw(rev);
  float c; asm("v_cos_f32 %0, %1" : "=v"(c) : "v"(f)); return c;
}
__device__ __forceinline__ float log_hw(float x){
  float l; asm("v_log_f32 %0, %1" : "=v"(l) : "v"(x));
  return 0.69314718056f * l;
}
__device__ __forceinline__ float exp_hw(float x){
  float y = x * 1.44269504f;
  float e; asm("v_exp_f32 %0, %1" : "=v"(e) : "v"(y));
  return e;
}

// ================= k_pre: fused [gate-MFMA (blocks 0..1023)] + [fp32->bf16 cvt] (unchanged) ====
__global__ __launch_bounds__(256) void k_pre(
    const float* __restrict__ box, const float* __restrict__ WGw, const float* __restrict__ WGb,
    _Float16* __restrict__ wg16,
    const float* __restrict__ q, const float* __restrict__ k, const float* __restrict__ v,
    const float* __restrict__ wq, const float* __restrict__ wk, const float* __restrict__ wv,
    const float* __restrict__ wo,
    ushort_t* __restrict__ qb, ushort_t* __restrict__ kb, ushort_t* __restrict__ vb,
    ushort_t* __restrict__ wqb, ushort_t* __restrict__ wkb, ushort_t* __restrict__ wvb,
    ushort_t* __restrict__ wob){
  const int t = threadIdx.x;
  if (blockIdx.x >= 1024){
    int gi = (blockIdx.x - 1024)*256 + t;
    const float* s; ushort_t* d; int off;
    if (gi < 196608){
      int seg = gi >> 16;
      off = (gi & 65535)*8;
      s = seg==0 ? q : seg==1 ? k : v;
      d = seg==0 ? qb : seg==1 ? kb : vb;
    } else {
      int g2 = gi - 196608;
      int seg = g2 >> 15;
      off = (g2 & 32767)*8;
      s = seg==0 ? wq : seg==1 ? wk : seg==2 ? wv : wo;
      d = seg==0 ? wqb : seg==1 ? wkb : seg==2 ? wvb : wob;
    }
    float4 a = *(const float4*)(s + off);
    float4 b = *(const float4*)(s + off + 4);
    u16x4 o0, o1;
    o0[0]=f2bf(a.x); o0[1]=f2bf(a.y); o0[2]=f2bf(a.z); o0[3]=f2bf(a.w);
    o1[0]=f2bf(b.x); o1[1]=f2bf(b.y); o1[2]=f2bf(b.z); o1[3]=f2bf(b.w);
    *(u16x4*)(d + off) = o0;
    *(u16x4*)(d + off + 4) = o1;
    return;
  }
  __shared__ float arr[4][1024];
  #pragma unroll
  for (int u=0; u<4; u++){
    int idx = u*256 + t;
    float4 b4 = *(const float4*)(box + idx*4);
    arr[0][idx] = (b4.x + b4.z)*0.5f;
    arr[1][idx] = (b4.y + b4.w)*0.5f;
    arr[2][idx] = log_hw(b4.z - b4.x + 1.0f);
    arr[3][idx] = log_hw(b4.w - b4.y + 1.0f);
  }
  const int i = blockIdx.x;
  const int lane = t & 63, w = t >> 6, li = lane & 15, g = lane >> 4;
  float4 bi = *(const float4*)(box + i*4);
  float wi = bi.z - bi.x + 1.0f, hi = bi.w - bi.y + 1.0f;
  float Pi = (g==0) ? (bi.x+bi.z)*0.5f : (g==1) ? (bi.y+bi.w)*0.5f
           : (g==2) ? log_hw(wi) : log_hw(hi);
  float Ri = (g==0) ? 1.0f/wi : (g==1) ? 1.0f/hi : 1.0f;
  const bool doLog = (g < 2);
  bf16x8 wfs = {}, wfc = {};
  float wgb_li = 0.0f;
  if (li < 8){
    #pragma unroll
    for (int e=0; e<8; e++){
      wfs[e] = (__bf16)WGw[li*64 + g*8 + e];
      wfc[e] = (__bf16)WGw[li*64 + 32 + g*8 + e];
    }
    wgb_li = WGb[li];
  }
  __syncthreads();
  const float* parr = &arr[g][0];
  const float DMrev[8] = {15.9154943f, 6.7115094f, 2.8302196f, 1.1934938f,
                          0.5032921f, 0.2122365f, 0.08949941f, 0.0377416f};
  const int jbeg = w*256;
  for (int it=0; it<16; ++it){
    int j = jbeg + it*16 + li;
    float diff = (Pi - parr[j])*Ri;
    float lg = log_hw(fmaxf(fabsf(diff), 1e-3f));
    float dv = doLog ? lg : diff;
    bf16x8 afs, afc;
    #pragma unroll
    for (int e=0; e<8; e++){
      float rev = dv * DMrev[e];
      afs[e] = (__bf16)sin_rev(rev);
      afc[e] = (__bf16)cos_rev(rev);
    }
    f32x4 acc = (f32x4){0.f,0.f,0.f,0.f};
    acc = __builtin_amdgcn_mfma_f32_16x16x32_bf16(afs, wfs, acc, 0,0,0);
    acc = __builtin_amdgcn_mfma_f32_16x16x32_bf16(afc, wfc, acc, 0,0,0);
    if (li < 8){
      f16x4 o;
      #pragma unroll
      for (int r=0; r<4; r++)
        o[r] = (_Float16)fmaxf(acc[r] + wgb_li, 6.103515625e-05f);
      *(f16x4*)(wg16 + (((size_t)li<<20) + ((size_t)i<<10) + jbeg + it*16 + g*4)) = o;
    }
  }
}

// ================= MFMA QKV projection (unchanged) =================
__global__ __launch_bounds__(128) void k_mm_qkv(
    const ushort_t* __restrict__ Aq, const ushort_t* __restrict__ Ak, const ushort_t* __restrict__ Av,
    const ushort_t* __restrict__ Wqb, const ushort_t* __restrict__ Wkb, const ushort_t* __restrict__ Wvb,
    const float* __restrict__ bq, const float* __restrict__ bk, const float* __restrict__ bv,
    ushort_t* __restrict__ Qb, ushort_t* __restrict__ Kb, ushort_t* __restrict__ Vt){
  const int z = blockIdx.z;
  const ushort_t* A = z==0 ? Aq : z==1 ? Ak : Av;
  const ushort_t* W = z==0 ? Wqb : z==1 ? Wkb : Wvb;
  const float* bias = z==0 ? bq : z==1 ? bk : bv;
  const int t = threadIdx.x, lane = t & 63, w = t >> 6;
  const int li = lane & 15, g = lane >> 4;
  const int m0 = blockIdx.y*32;
  const int n0 = blockIdx.x*64 + w*32;
  const ushort_t* ar = A + (size_t)(m0+li)*DMODEL + g*8;
  const ushort_t* wr = W + (size_t)(n0+li)*DMODEL + g*8;
  f32x4 acc[2][2] = {};
  if (z < 2){
    #pragma unroll
    for (int k0=0; k0<DMODEL; k0+=64){
      bf16x8 wf0a = *(const bf16x8*)(wr + k0);
      bf16x8 wf0b = *(const bf16x8*)(wr + k0 + 32);
      bf16x8 wf1a = *(const bf16x8*)(wr + 16*DMODEL + k0);
      bf16x8 wf1b = *(const bf16x8*)(wr + 16*DMODEL + k0 + 32);
      bf16x8 af0a = *(const bf16x8*)(ar + k0);
      bf16x8 af0b = *(const bf16x8*)(ar + k0 + 32);
      bf16x8 af1a = *(const bf16x8*)(ar + 16*DMODEL + k0);
      bf16x8 af1b = *(const bf16x8*)(ar + 16*DMODEL + k0 + 32);
      acc[0][0] = __builtin_amdgcn_mfma_f32_16x16x32_bf16(wf0a, af0a, acc[0][0], 0,0,0);
      acc[0][0] = __builtin_amdgcn_mfma_f32_16x16x32_bf16(wf0b, af0b, acc[0][0], 0,0,0);
      acc[0][1] = __builtin_amdgcn_mfma_f32_16x16x32_bf16(wf0a, af1a, acc[0][1], 0,0,0);
      acc[0][1] = __builtin_amdgcn_mfma_f32_16x16x32_bf16(wf0b, af1b, acc[0][1], 0,0,0);
      acc[1][0] = __builtin_amdgcn_mfma_f32_16x16x32_bf16(wf1a, af0a, acc[1][0], 0,0,0);
      acc[1][0] = __builtin_amdgcn_mfma_f32_16x16x32_bf16(wf1b, af0b, acc[1][0], 0,0,0);
      acc[1][1] = __builtin_amdgcn_mfma_f32_16x16x32_bf16(wf1a, af1a, acc[1][1], 0,0,0);
      acc[1][1] = __builtin_amdgcn_mfma_f32_16x16x32_bf16(wf1b, af1b, acc[1][1], 0,0,0);
    }
    ushort_t* C = z ? Kb : Qb;
    #pragma unroll
    for (int nf=0; nf<2; nf++){
      int n = n0 + nf*16 + g*4;
      float4 b4 = *(const float4*)(bias + n);
      const float* bp = (const float*)&b4;
      #pragma unroll
      for (int mf=0; mf<2; mf++){
        int m = m0 + mf*16 + li;
        u16x4 o;
        #pragma unroll
        for (int r=0; r<4; r++) o[r] = f2bf(acc[nf][mf][r] + bp[r]);
        *(u16x4*)(C + (size_t)m*DMODEL + n) = o;
      }
    }
  } else {
    #pragma unroll
    for (int k0=0; k0<DMODEL; k0+=64){
      bf16x8 wf0a = *(const bf16x8*)(wr + k0);
      bf16x8 wf0b = *(const bf16x8*)(wr + k0 + 32);
      bf16x8 wf1a = *(const bf16x8*)(wr + 16*DMODEL + k0);
      bf16x8 wf1b = *(const bf16x8*)(wr + 16*DMODEL + k0 + 32);
      bf16x8 af0a = *(const bf16x8*)(ar + k0);
      bf16x8 af0b = *(const bf16x8*)(ar + k0 + 32);
      bf16x8 af1a = *(const bf16x8*)(ar + 16*DMODEL + k0);
      bf16x8 af1b = *(const bf16x8*)(ar + 16*DMODEL + k0 + 32);
      acc[0][0] = __builtin_amdgcn_mfma_f32_16x16x32_bf16(af0a, wf0a, acc[0][0], 0,0,0);
      acc[0][0] = __builtin_amdgcn_mfma_f32_16x16x32_bf16(af0b, wf0b, acc[0][0], 0,0,0);
      acc[0][1] = __builtin_amdgcn_mfma_f32_16x16x32_bf16(af0a, wf1a, acc[0][1], 0,0,0);
      acc[0][1] = __builtin_amdgcn_mfma_f32_16x16x32_bf16(af0b, wf1b, acc[0][1], 0,0,0);
      acc[1][0] = __builtin_amdgcn_mfma_f32_16x16x32_bf16(af1a, wf0a, acc[1][0], 0,0,0);
      acc[1][0] = __builtin_amdgcn_mfma_f32_16x16x32_bf16(af1b, wf0b, acc[1][0], 0,0,0);
      acc[1][1] = __builtin_amdgcn_mfma_f32_16x16x32_bf16(af1a, wf1a, acc[1][1], 0,0,0);
      acc[1][1] = __builtin_amdgcn_mfma_f32_16x16x32_bf16(af1b, wf1b, acc[1][1], 0,0,0);
    }
    #pragma unroll
    for (int mf=0; mf<2; mf++){
      int m = m0 + mf*16 + g*4;
      #pragma unroll
      for (int nf=0; nf<2; nf++){
        int n = n0 + nf*16 + li;
        float bn = bias[n];
        u16x4 o;
        #pragma unroll
        for (int r=0; r<4; r++) o[r] = f2bf(acc[mf][nf][r] + bn);
        *(u16x4*)(Vt + (((size_t)(n>>6))<<16) + ((size_t)(n&63)<<10) + m) = o;
      }
    }
  }
}

// ================= k_attn3: LDS-shared K/V attention =================
// Block = (i-tile-group, h, sp): 8 waves stage K[256j][64dk] + V[64dk][256j] into LDS once,
// then each wave computes its 16-row i-tile entirely from LDS (wg16 streamed from global).
// Global K/V traffic: 128 MB -> 16 MB.  256 blocks = 1/CU, 2048 waves.
__global__ __launch_bounds__(512) void k_attn3(const ushort_t* __restrict__ Qb,
     const ushort_t* __restrict__ Kb, const ushort_t* __restrict__ Vt,
     const _Float16* __restrict__ wg, ushort_t* __restrict__ Xpt, float* __restrict__ rsp){
  __shared__ ushort_t Ks[256*68];   // stride 68 halfs: 2-way-free banks on frag reads
  __shared__ ushort_t Vs[64*264];   // stride 264 halfs: 2-way-free banks on frag reads
  const int t = threadIdx.x;
  const int itg = blockIdx.x, h = blockIdx.y, sp = blockIdx.z;
  const int jbeg = sp*JQ;
  {
    const int r = t >> 3, c = (t & 7)*8;
    #pragma unroll
    for (int p=0; p<4; p++){
      u16x8 kv = *(const u16x8*)(Kb + (size_t)(jbeg + p*64 + r)*DMODEL + h*DKH + c);
      *(u16x8*)(Ks + (p*64 + r)*68 + c) = kv;
      u16x8 vv = *(const u16x8*)(Vt + ((size_t)h<<16) + (size_t)r*NTOK + jbeg + p*64 + c);
      *(u16x8*)(Vs + r*264 + p*64 + c) = vv;
    }
  }
  const int lane = t & 63, w = t >> 6;
  const int i0 = (itg*8 + w)*16;
  const int li = lane & 15, g = lane >> 4;
  const ushort_t* qp = Qb + (size_t)(i0+li)*DMODEL + h*DKH + g*8;
  bf16x8 qf0 = *(const bf16x8*)(qp);
  bf16x8 qf1 = *(const bf16x8*)(qp + 32);
  const _Float16* gbase = wg + ((size_t)h<<20) + ((size_t)(i0+li)<<10) + jbeg + g*4;
  f32x4 xacc[4];
  #pragma unroll
  for (int mf=0; mf<4; mf++) xacc[mf] = (f32x4){0.f,0.f,0.f,0.f};
  float rsum = 0.f;
  __syncthreads();
  #pragma unroll
  for (int jj = 0; jj < JQ; jj += 32){
    const ushort_t* kp = Ks + (jj + li)*68 + g*8;
    bf16x8 a00 = *(const bf16x8*)(kp);
    bf16x8 a01 = *(const bf16x8*)(kp + 32);
    bf16x8 a10 = *(const bf16x8*)(kp + 16*68);
    bf16x8 a11 = *(const bf16x8*)(kp + 16*68 + 32);
    f32x4 s0 = (f32x4){0.f,0.f,0.f,0.f};
    f32x4 s1 = (f32x4){0.f,0.f,0.f,0.f};
    s0 = __builtin_amdgcn_mfma_f32_16x16x32_bf16(a00, qf0, s0, 0,0,0);
    s0 = __builtin_amdgcn_mfma_f32_16x16x32_bf16(a01, qf1, s0, 0,0,0);
    s1 = __builtin_amdgcn_mfma_f32_16x16x32_bf16(a10, qf0, s1, 0,0,0);
    s1 = __builtin_amdgcn_mfma_f32_16x16x32_bf16(a11, qf1, s1, 0,0,0);
    f16x4 g0 = *(const f16x4*)(gbase + jj);
    f16x4 g1 = *(const f16x4*)(gbase + jj + 16);
    float p[8];
    #pragma unroll
    for (int r=0; r<4; r++){ p[r]   = (float)g0[r] * exp_hw(s0[r]*0.125f); rsum += p[r]; }
    #pragma unroll
    for (int r=0; r<4; r++){ p[4+r] = (float)g1[r] * exp_hw(s1[r]*0.125f); rsum += p[4+r]; }
    bf16x8 pb;
    pb[0]=(__bf16)p[0]; pb[1]=(__bf16)p[1]; pb[2]=(__bf16)p[2]; pb[3]=(__bf16)p[3];
    pb[4]=(__bf16)p[4]; pb[5]=(__bf16)p[5]; pb[6]=(__bf16)p[6]; pb[7]=(__bf16)p[7];
    #pragma unroll
    for (int mf=0; mf<4; mf++){
      const ushort_t* vp = Vs + (size_t)(li + mf*16)*264 + jj + g*4;
      bf16x4 lo = *(const bf16x4*)(vp);
      bf16x4 hi = *(const bf16x4*)(vp + 16);
      bf16x8 vf = __builtin_shufflevector(lo, hi, 0,1,2,3,4,5,6,7);
      xacc[mf] = __builtin_amdgcn_mfma_f32_16x16x32_bf16(vf, pb, xacc[mf], 0,0,0);
    }
  }
  rsum += __shfl_xor(rsum, 16, 64);
  rsum += __shfl_xor(rsum, 32, 64);
  if (lane < 16) rsp[((size_t)sp*NHEAD + h)*NTOK + i0 + li] = rsum;
  // transpose via LDS aliased onto Ks (dead after compute); 8 waves x 16 x 68 floats = 34816 B = sizeof(Ks)
  __syncthreads();
  float* xw = (float*)Ks + w*(16*68);
  #pragma unroll
  for (int mf=0; mf<4; mf++)
    *(f32x4*)&xw[li*68 + mf*16 + g*4] = xacc[mf];
  __builtin_amdgcn_s_waitcnt(0);   // lgkmcnt(0) for own-wave LDS writes
  float xv[16];
  #pragma unroll
  for (int r=0; r<16; r++) xv[r] = xw[r*68 + lane];
  u16x8 o0, o1;
  #pragma unroll
  for (int r=0; r<8; r++){ o0[r] = f2bf(xv[r]); o1[r] = f2bf(xv[8+r]); }
  ushort_t* xp = Xpt + (((size_t)sp*NHEAD + h)*DKH + lane)*NTOK + i0;
  *(u16x8*)(xp)     = o0;
  *(u16x8*)(xp + 8) = o1;
}

// ================= combine + scrambled-reshape LN (unchanged) =================
__global__ __launch_bounds__(256) void k_ln0c(const ushort_t* __restrict__ Xpt,
        const float* __restrict__ rsp, const float* __restrict__ resid,
        const float* __restrict__ g, const float* __restrict__ b,
        float* __restrict__ out0, ushort_t* __restrict__ out0b){
  const int n = blockIdx.x, t = threadIdx.x;
  const int h = n >> 7, dk = (n >> 1) & 63, mo = (n & 1)*512;
  const int i0 = mo + t, i1 = mo + t + 256;
  float s0v=0.f, s1v=0.f, r0=0.f, r1=0.f;
  #pragma unroll
  for (int sp=0; sp<NSPLIT; sp++){
    const ushort_t* base = Xpt + (((size_t)sp*NHEAD + h)*DKH + dk)*NTOK;
    s0v += bf2f(base[i0]);
    s1v += bf2f(base[i1]);
    const float* rb = rsp + ((size_t)sp*NHEAD + h)*NTOK;
    r0 += rb[i0];
    r1 += rb[i1];
  }
  float x0 = s0v/r0 + resid[(size_t)n*DMODEL + t];
  float x1 = s1v/r1 + resid[(size_t)n*DMODEL + t + 256];
  __shared__ float red[8];
  float s = wave_sum_f(x0 + x1);
  float q = wave_sum_f(x0*x0 + x1*x1);
  int wid = t >> 6, lane = t & 63;
  if (lane == 0){ red[wid] = s; red[4+wid] = q; }
  __syncthreads();
  float S = red[0]+red[1]+red[2]+red[3];
  float Q = red[4]+red[5]+red[6]+red[7];
  float mean = S * (1.0f/512.0f);
  float var = Q * (1.0f/512.0f) - mean*mean;
  float rs = rsqrtf(var + 1e-5f);
  float y0 = (x0-mean)*rs*g[t] + b[t];
  float y1 = (x1-mean)*rs*g[t+256] + b[t+256];
  out0[(size_t)n*DMODEL + t]        = y0;
  out0[(size_t)n*DMODEL + t + 256]  = y1;
  out0b[(size_t)n*DMODEL + t]       = f2bf(y0);
  out0b[(size_t)n*DMODEL + t + 256] = f2bf(y1);
}

// ================= O-projection + residual + final LN (unchanged) =================
__global__ __launch_bounds__(512) void k_mm_o_ln(
    const ushort_t* __restrict__ A, const ushort_t* __restrict__ W,
    const float* __restrict__ bo, const float* __restrict__ add,
    const float* __restrict__ lng, const float* __restrict__ lnb, float* __restrict__ out){
  const int t = threadIdx.x, lane = t & 63, w = t >> 6;
  const int li = lane & 15, g = lane >> 4;
  const int m0 = blockIdx.x*16;
  const int n0 = w*64;
  const ushort_t* ar = A + (size_t)(m0+li)*DMODEL + g*8;
  const ushort_t* wr = W + (size_t)(n0+li)*DMODEL + g*8;
  f32x4 acc[4] = {};
  #pragma unroll
  for (int k0=0; k0<DMODEL; k0+=64){
    bf16x8 afa = *(const bf16x8*)(ar + k0);
    bf16x8 afb = *(const bf16x8*)(ar + k0 + 32);
    #pragma unroll
    for (int nf=0; nf<4; nf++){
      const ushort_t* wp = wr + (size_t)nf*16*DMODEL + k0;
      bf16x8 wfa = *(const bf16x8*)(wp);
      bf16x8 wfb = *(const bf16x8*)(wp + 32);
      acc[nf] = __builtin_amdgcn_mfma_f32_16x16x32_bf16(wfa, afa, acc[nf], 0,0,0);
      acc[nf] = __builtin_amdgcn_mfma_f32_16x16x32_bf16(wfb, afb, acc[nf], 0,0,0);
    }
  }
  const int m = m0 + li;
  float s = 0.f, qq = 0.f;
  f32x4 v[4];
  #pragma unroll
  for (int nf=0; nf<4; nf++){
    int n = n0 + nf*16 + g*4;
    f32x4 b4 = *(const f32x4*)(bo + n);
    f32x4 a4 = *(const f32x4*)(add + (size_t)m*DMODEL + n);
    #pragma unroll
    for (int r=0; r<4; r++){
      float x = acc[nf][r] + b4[r] + a4[r];
      v[nf][r] = x; s += x; qq += x*x;
    }
  }
  s  += __shfl_xor(s, 16, 64);  s  += __shfl_xor(s, 32, 64);
  qq += __shfl_xor(qq, 16, 64); qq += __shfl_xor(qq, 32, 64);
  __shared__ float red[8][16][2];
  if (g == 0){ red[w][li][0] = s; red[w][li][1] = qq; }
  __syncthreads();
  float S = 0.f, Q = 0.f;
  #pragma unroll
  for (int u=0; u<8; u++){ S += red[u][li][0]; Q += red[u][li][1]; }
  float mean = S * (1.0f/512.0f);
  float var = Q * (1.0f/512.0f) - mean*mean;
  float rs = rsqrtf(var + 1e-5f);
  #pragma unroll
  for (int nf=0; nf<4; nf++){
    int n = n0 + nf*16 + g*4;
    f32x4 g4 = *(const f32x4*)(lng + n);
    f32x4 be = *(const f32x4*)(lnb + n);
    f32x4 o;
    #pragma unroll
    for (int r=0; r<4; r++) o[r] = (v[nf][r]-mean)*rs*g4[r] + be[r];
    *(f32x4*)(out + (size_t)m*DMODEL + n) = o;
  }
}

extern "C" void kernel_launch(void* const* d_in, const int* in_sizes, int n_in,
                              void* d_out, int out_size, void* d_ws, size_t ws_size,
                              hipStream_t stream){
  (void)in_sizes; (void)n_in; (void)out_size; (void)ws_size;
  const float* in_q = (const float*)d_in[0];
  const float* in_k = (const float*)d_in[1];
  const float* in_v = (const float*)d_in[2];
  const float* box  = (const float*)d_in[3];
  const float* Wq   = (const float*)d_in[4];
  const float* bq   = (const float*)d_in[5];
  const float* Wk   = (const float*)d_in[6];
  const float* bk   = (const float*)d_in[7];
  const float* Wv   = (const float*)d_in[8];
  const float* bv   = (const float*)d_in[9];
  const float* Wo   = (const float*)d_in[10];
  const float* bo   = (const float*)d_in[11];
  const float* WGw  = (const float*)d_in[12];
  const float* WGb  = (const float*)d_in[13];
  const float* ln0g = (const float*)d_in[14];
  const float* ln0b = (const float*)d_in[15];
  const float* lng  = (const float*)d_in[16];
  const float* lnb  = (const float*)d_in[17];

  float* ws = (float*)d_ws;
  ushort_t* Abq  = (ushort_t*)(ws + 0);
  ushort_t* Abk  = (ushort_t*)(ws + 262144);
  ushort_t* Abv  = (ushort_t*)(ws + 524288);
  ushort_t* Wqb  = (ushort_t*)(ws + 786432);
  ushort_t* Wkb  = (ushort_t*)(ws + 917504);
  ushort_t* Wvb  = (ushort_t*)(ws + 1048576);
  ushort_t* Wob  = (ushort_t*)(ws + 1179648);
  ushort_t* Qb   = (ushort_t*)(ws + 1310720);
  ushort_t* Kb   = (ushort_t*)(ws + 1572864);
  ushort_t* Vt   = (ushort_t*)(ws + 1835008);
  _Float16* wg16 = (_Float16*)(ws + 2097152);
  ushort_t* Xpt  = (ushort_t*)(ws + 6291456);
  float*    rsp  = ws + 8388608;
  float*    out0 = ws + 8421376;
  ushort_t* out0b= (ushort_t*)(ws + 8945664);
  float*    out  = (float*)d_out;

  k_pre<<<dim3(2304), dim3(256), 0, stream>>>(box, WGw, WGb, wg16,
            in_q, in_k, in_v, Wq, Wk, Wv, Wo,
            Abq, Abk, Abv, Wqb, Wkb, Wvb, Wob);
  k_mm_qkv<<<dim3(8,32,3), dim3(128), 0, stream>>>(Abq, Abk, Abv, Wqb, Wkb, Wvb,
            bq, bk, bv, Qb, Kb, Vt);
  k_attn3<<<dim3(8,8,4), dim3(512), 0, stream>>>(Qb, Kb, Vt, wg16, Xpt, rsp);
  k_ln0c<<<dim3(1024), dim3(256), 0, stream>>>(Xpt, rsp, in_q, ln0g, ln0b, out0, out0b);
  k_mm_o_ln<<<dim3(64), dim3(512), 0, stream>>>(out0b, Wob, bo, out0, lng, lnb, out);
}